// Round 3
// baseline (454.899 us; speedup 1.0000x reference)
//
#include <hip/hip_runtime.h>
#include <hip/hip_bf16.h>
#include <cstdint>

#define B_  4
#define N_  4096
#define C_  256
#define CD_ 64

typedef unsigned short ushort_t;
typedef __bf16 bf16x8 __attribute__((ext_vector_type(8)));
typedef float f32x4 __attribute__((ext_vector_type(4)));

typedef const __attribute__((address_space(1))) void* gas_t;
typedef __attribute__((address_space(3))) void* las_t;

// (1/sqrt(256)) * log2(e): folded into K projection so S' = S_true * log2(e)
static constexpr float SCALE_LOG2E = 0.09016844005556021f;

__device__ __forceinline__ ushort_t f2bf(float x) {
    union { float f; unsigned u; } v; v.f = x;
    unsigned u = v.u;
    unsigned r = (u + 0x7fffu + ((u >> 16) & 1u)) >> 16;  // round-nearest-even
    return (ushort_t)r;
}

__device__ __forceinline__ bf16x8 ld_bf8(const ushort_t* p) {
    return *reinterpret_cast<const bf16x8*>(p);
}

// ---------------------------------------------------------------------------
// Projection producing TRANSPOSED bf16 output dst[b][n][o]  (for Qt, Kt)
// dst = (W @ X + bias) * outScale      (unchanged — proven correct)
// ---------------------------------------------------------------------------
__global__ void proj_t_kernel(const float* __restrict__ X, const float* __restrict__ W,
                              const float* __restrict__ bias, ushort_t* __restrict__ dst,
                              int Cin, float outScale) {
    __shared__ float sX[16][68];
    __shared__ float sW[64][17];
    const int tid = threadIdx.x;
    const int b = blockIdx.z;
    const int oBase = blockIdx.y * 64;
    const int nBase = blockIdx.x * 64;
    const int tx = tid & 15, ty = tid >> 4;
    float acc[4][4] = {};
    for (int k0 = 0; k0 < Cin; k0 += 16) {
        int kk = tid >> 4, nn = (tid & 15) * 4;
        float4 xv = *(const float4*)(X + ((size_t)b * Cin + k0 + kk) * N_ + nBase + nn);
        *(float4*)&sX[kk][nn] = xv;
        int oo = tid >> 2, kc = (tid & 3) * 4;
        float4 wv = *(const float4*)(W + (size_t)(oBase + oo) * Cin + k0 + kc);
        sW[oo][kc + 0] = wv.x; sW[oo][kc + 1] = wv.y;
        sW[oo][kc + 2] = wv.z; sW[oo][kc + 3] = wv.w;
        __syncthreads();
#pragma unroll
        for (int kk2 = 0; kk2 < 16; ++kk2) {
            float4 xr4 = *(float4*)&sX[kk2][tx * 4];
            float xr[4] = {xr4.x, xr4.y, xr4.z, xr4.w};
#pragma unroll
            for (int i = 0; i < 4; ++i) {
                float wv2 = sW[ty * 4 + i][kk2];
#pragma unroll
                for (int j = 0; j < 4; ++j) acc[i][j] += wv2 * xr[j];
            }
        }
        __syncthreads();
    }
    float4 bi4 = *(const float4*)(bias + oBase + ty * 4);
    float bia[4] = {bi4.x, bi4.y, bi4.z, bi4.w};
#pragma unroll
    for (int j = 0; j < 4; ++j) {
        int n = nBase + tx * 4 + j;
        unsigned p0 = f2bf((acc[0][j] + bia[0]) * outScale);
        unsigned p1 = f2bf((acc[1][j] + bia[1]) * outScale);
        unsigned p2 = f2bf((acc[2][j] + bia[2]) * outScale);
        unsigned p3 = f2bf((acc[3][j] + bia[3]) * outScale);
        uint2 pk; pk.x = p0 | (p1 << 16); pk.y = p2 | (p3 << 16);
        *(uint2*)(dst + ((size_t)b * N_ + n) * C_ + oBase + ty * 4) = pk;
    }
}

// ---------------------------------------------------------------------------
// Projection producing NATURAL bf16 output dst[b][o][n]  (for V) — unchanged
// ---------------------------------------------------------------------------
__global__ void proj_n_kernel(const float* __restrict__ X, const float* __restrict__ W,
                              const float* __restrict__ bias, ushort_t* __restrict__ dst,
                              int Cin) {
    __shared__ float sX[16][68];
    __shared__ float sW[64][17];
    const int tid = threadIdx.x;
    const int b = blockIdx.z;
    const int oBase = blockIdx.y * 64;
    const int nBase = blockIdx.x * 64;
    const int tx = tid & 15, ty = tid >> 4;
    float acc[4][4] = {};
    for (int k0 = 0; k0 < Cin; k0 += 16) {
        int kk = tid >> 4, nn = (tid & 15) * 4;
        float4 xv = *(const float4*)(X + ((size_t)b * Cin + k0 + kk) * N_ + nBase + nn);
        *(float4*)&sX[kk][nn] = xv;
        int oo = tid >> 2, kc = (tid & 3) * 4;
        float4 wv = *(const float4*)(W + (size_t)(oBase + oo) * Cin + k0 + kc);
        sW[oo][kc + 0] = wv.x; sW[oo][kc + 1] = wv.y;
        sW[oo][kc + 2] = wv.z; sW[oo][kc + 3] = wv.w;
        __syncthreads();
#pragma unroll
        for (int kk2 = 0; kk2 < 16; ++kk2) {
            float4 xr4 = *(float4*)&sX[kk2][tx * 4];
            float xr[4] = {xr4.x, xr4.y, xr4.z, xr4.w};
#pragma unroll
            for (int i = 0; i < 4; ++i) {
                float wv2 = sW[ty * 4 + i][kk2];
#pragma unroll
                for (int j = 0; j < 4; ++j) acc[i][j] += wv2 * xr[j];
            }
        }
        __syncthreads();
    }
#pragma unroll
    for (int i = 0; i < 4; ++i) {
        int o = oBase + ty * 4 + i;
        float bia = bias[o];
        unsigned p0 = f2bf(acc[i][0] + bia);
        unsigned p1 = f2bf(acc[i][1] + bia);
        unsigned p2 = f2bf(acc[i][2] + bia);
        unsigned p3 = f2bf(acc[i][3] + bia);
        uint2 pk; pk.x = p0 | (p1 << 16); pk.y = p2 | (p3 << 16);
        *(uint2*)(dst + ((size_t)b * C_ + o) * N_ + nBase + tx * 4) = pk;
    }
}

// ---------------------------------------------------------------------------
// Pass A: l[b][i] = sum_j exp2(S'[i][j]).  m97-style GEMM, 128x128 tile,
// BK=64, global_load_lds(16B) with XOR-swizzled source chunks.
// grid (32 j-tiles, 32 i-tiles, B), block 256 (4 waves, 2x2 of 64x64).
// ---------------------------------------------------------------------------
__global__ __launch_bounds__(256, 5)
void stats_kernel(const ushort_t* __restrict__ Kt, const ushort_t* __restrict__ Qt,
                  float* __restrict__ l) {
    __shared__ ushort_t sA[128 * 64];   // [row i][8 chunks of 8 bf16, swizzled]
    __shared__ ushort_t sB[128 * 64];   // [row j][...]
    const int tid = threadIdx.x;
    const int lane = tid & 63, g = lane >> 4, c16 = lane & 15;
    const int w = tid >> 6, wi = w >> 1, wj = w & 1;
    const int b = blockIdx.z;
    const int ib = blockIdx.y * 128, jb = blockIdx.x * 128;
    f32x4 acc[4][4];
#pragma unroll
    for (int mt = 0; mt < 4; ++mt)
#pragma unroll
        for (int nt = 0; nt < 4; ++nt) acc[mt][nt] = (f32x4){0.f, 0.f, 0.f, 0.f};

    const int srow = tid >> 3;     // 0..31, round q adds q*32
    const int sc4 = tid & 7;       // destination chunk slot within row

    for (int k0 = 0; k0 < 256; k0 += 64) {
#pragma unroll
        for (int q = 0; q < 4; ++q) {
            const int row = q * 32 + srow;
            const int gc = sc4 ^ (row & 7);                 // swizzled source chunk
            const ushort_t* srcA = Kt + ((size_t)(b * N_ + ib + row)) * C_ + k0 + gc * 8;
            const ushort_t* srcB = Qt + ((size_t)(b * N_ + jb + row)) * C_ + k0 + gc * 8;
            __builtin_amdgcn_global_load_lds((gas_t)srcA, (las_t)&sA[(q * 256 + tid) * 8], 16, 0, 0);
            __builtin_amdgcn_global_load_lds((gas_t)srcB, (las_t)&sB[(q * 256 + tid) * 8], 16, 0, 0);
        }
        __syncthreads();
#pragma unroll
        for (int ks = 0; ks < 2; ++ks) {
            bf16x8 af[4], bf[4];
#pragma unroll
            for (int mt = 0; mt < 4; ++mt) {
                const int row = wi * 64 + mt * 16 + c16;
                af[mt] = *(const bf16x8*)&sA[row * 64 + (((ks * 4 + g) ^ (row & 7)) * 8)];
            }
#pragma unroll
            for (int nt = 0; nt < 4; ++nt) {
                const int row = wj * 64 + nt * 16 + c16;
                bf[nt] = *(const bf16x8*)&sB[row * 64 + (((ks * 4 + g) ^ (row & 7)) * 8)];
            }
#pragma unroll
            for (int mt = 0; mt < 4; ++mt)
#pragma unroll
                for (int nt = 0; nt < 4; ++nt)
                    acc[mt][nt] = __builtin_amdgcn_mfma_f32_16x16x32_bf16(af[mt], bf[nt], acc[mt][nt], 0, 0, 0);
        }
        __syncthreads();
    }
    // epilogue: e = exp2(S'), row-sum over 128 j of this block, atomic into l
#pragma unroll
    for (int mt = 0; mt < 4; ++mt) {
#pragma unroll
        for (int r = 0; r < 4; ++r) {
            float s = exp2f(acc[mt][0][r]) + exp2f(acc[mt][1][r])
                    + exp2f(acc[mt][2][r]) + exp2f(acc[mt][3][r]);
            s += __shfl_xor(s, 1, 64);
            s += __shfl_xor(s, 2, 64);
            s += __shfl_xor(s, 4, 64);
            s += __shfl_xor(s, 8, 64);
            if (c16 == 0)
                atomicAdd(l + (size_t)b * N_ + ib + wi * 64 + mt * 16 + g * 4 + r, s);
        }
    }
}

// ---------------------------------------------------------------------------
// Pass B v3: O[c][j] += sum_i V[c][i] * exp2(S'[i][j] - log2 l_i).
// Block = 64 j x all 256 c, i-chunk = 128, i-split 4 -> 1024 blocks
// (3 blocks/CU LDS-capped, 24 waves/CU).  Padded LDS (regular stores ->
// padding legal): sQ[64][264], sP[64][136] -- frag-read phases conflict-free.
// Serial-chain shortening: Kt frags + l(float4, direct global + log2f) loaded
// ABOVE barrier A; all 8 V-loads issued BEFORE barrier B.
// grid (64 j-tiles, 4 i-quarters, B), block 512; atomics onto
// residual-prefilled d_out.
// ---------------------------------------------------------------------------
__global__ __launch_bounds__(512, 6)
void out_kernel(const ushort_t* __restrict__ Kt, const ushort_t* __restrict__ Qt,
                const ushort_t* __restrict__ V, const float* __restrict__ l,
                float* __restrict__ dout) {
    __shared__ ushort_t sQ[64][264];   // Qt j-tile [jloc][c], +8 pad (33 KB)
    __shared__ ushort_t sP[64][136];   // P^T [jloc][iloc], +8 pad (17 KB)
    const int tid = threadIdx.x;
    const int w = tid >> 6, lane = tid & 63, g = lane >> 4, c16 = lane & 15;
    const int b = blockIdx.z;
    const int jb = blockIdx.x * 64;
    const int ibase = blockIdx.y * 1024;

    // stage Qt j-tile once (padded rows; regular stores)
    {
        const int jl = tid >> 3, cp = (tid & 7) * 32;
        const ushort_t* src = Qt + ((size_t)(b * N_ + jb + jl)) * C_ + cp;
        uint4 a0 = *(const uint4*)(src);
        uint4 a1 = *(const uint4*)(src + 8);
        uint4 a2 = *(const uint4*)(src + 16);
        uint4 a3 = *(const uint4*)(src + 24);
        *(uint4*)&sQ[jl][cp + 0]  = a0;
        *(uint4*)&sQ[jl][cp + 8]  = a1;
        *(uint4*)&sQ[jl][cp + 16] = a2;
        *(uint4*)&sQ[jl][cp + 24] = a3;
    }
    f32x4 acc[2][4];
#pragma unroll
    for (int mt = 0; mt < 2; ++mt)
#pragma unroll
        for (int nt = 0; nt < 4; ++nt) acc[mt][nt] = (f32x4){0.f, 0.f, 0.f, 0.f};

    const int iw = w * 16;    // S-phase i rows within chunk
    const int cw = w * 32;    // PV-phase c base

    for (int ic = 0; ic < 8; ++ic) {
        const int i0 = ibase + ic * 128;
        // ---- early independent loads (above barrier A) ----
        const size_t krow = ((size_t)(b * N_ + i0 + iw + c16)) * C_ + g * 8;
        bf16x8 ka[8];
#pragma unroll
        for (int k = 0; k < 8; ++k) ka[k] = ld_bf8(Kt + krow + k * 32);
        float4 lr = *(const float4*)(l + (size_t)b * N_ + i0 + iw + g * 4);
        const float rv0 = log2f(lr.x), rv1 = log2f(lr.y),
                    rv2 = log2f(lr.z), rv3 = log2f(lr.w);
        __syncthreads();   // barrier A: prev chunk's PV done -> sP writable
        // ---- S phase ----
        f32x4 sa[4];
#pragma unroll
        for (int nt = 0; nt < 4; ++nt) sa[nt] = (f32x4){0.f, 0.f, 0.f, 0.f};
#pragma unroll
        for (int k = 0; k < 8; ++k) {
#pragma unroll
            for (int nt = 0; nt < 4; ++nt) {
                bf16x8 bv = *(const bf16x8*)&sQ[nt * 16 + c16][k * 32 + g * 8];
                sa[nt] = __builtin_amdgcn_mfma_f32_16x16x32_bf16(ka[k], bv, sa[nt], 0, 0, 0);
            }
        }
#pragma unroll
        for (int nt = 0; nt < 4; ++nt) {
            const int j = nt * 16 + c16;
            unsigned p0 = f2bf(exp2f(sa[nt][0] - rv0));
            unsigned p1 = f2bf(exp2f(sa[nt][1] - rv1));
            unsigned p2 = f2bf(exp2f(sa[nt][2] - rv2));
            unsigned p3 = f2bf(exp2f(sa[nt][3] - rv3));
            uint2 pk; pk.x = p0 | (p1 << 16); pk.y = p2 | (p3 << 16);
            *(uint2*)&sP[j][iw + g * 4] = pk;
        }
        // ---- issue V loads for PV before barrier B ----
        bf16x8 va[4][2];
#pragma unroll
        for (int ks = 0; ks < 4; ++ks)
#pragma unroll
            for (int mt = 0; mt < 2; ++mt)
                va[ks][mt] = ld_bf8(V + ((size_t)(b * C_ + cw + mt * 16 + c16)) * N_ + i0 + ks * 32 + g * 8);
        __syncthreads();   // barrier B: sP ready
        // ---- PV phase ----
#pragma unroll
        for (int ks = 0; ks < 4; ++ks) {
#pragma unroll
            for (int nt = 0; nt < 4; ++nt) {
                bf16x8 pb = *(const bf16x8*)&sP[nt * 16 + c16][ks * 32 + g * 8];
#pragma unroll
                for (int mt = 0; mt < 2; ++mt)
                    acc[mt][nt] = __builtin_amdgcn_mfma_f32_16x16x32_bf16(va[ks][mt], pb, acc[mt][nt], 0, 0, 0);
            }
        }
    }
#pragma unroll
    for (int mt = 0; mt < 2; ++mt)
#pragma unroll
        for (int nt = 0; nt < 4; ++nt)
#pragma unroll
            for (int r = 0; r < 4; ++r) {
                const int c = cw + mt * 16 + g * 4 + r;
                const int j = jb + nt * 16 + c16;
                atomicAdd(dout + ((size_t)b * C_ + c) * N_ + j, acc[mt][nt][r]);
            }
}

extern "C" void kernel_launch(void* const* d_in, const int* in_sizes, int n_in,
                              void* d_out, int out_size, void* d_ws, size_t ws_size,
                              hipStream_t stream) {
    const float* x_s2  = (const float*)d_in[0];
    const float* x_dem = (const float*)d_in[1];
    const float* Wq = (const float*)d_in[2];
    const float* bq = (const float*)d_in[3];
    const float* Wk = (const float*)d_in[4];
    const float* bk = (const float*)d_in[5];
    const float* Wv = (const float*)d_in[6];
    const float* bv = (const float*)d_in[7];
    float* out = (float*)d_out;

    char* ws = (char*)d_ws;
    ushort_t* Qt = (ushort_t*)(ws);                               // [B][N][C] bf16, 8 MB
    ushort_t* Kt = (ushort_t*)(ws + (size_t)8  * 1024 * 1024);    // [B][N][C] bf16, pre-scaled
    ushort_t* Vm = (ushort_t*)(ws + (size_t)16 * 1024 * 1024);    // [B][C][N] bf16
    float*    lv = (float*)   (ws + (size_t)24 * 1024 * 1024);    // [B][N] row sums

    hipMemsetAsync(lv, 0, (size_t)B_ * N_ * sizeof(float), stream);
    // residual: pre-fill output with x_s2; out_kernel atomically adds O
    hipMemcpyAsync(out, x_s2, (size_t)B_ * C_ * N_ * sizeof(float),
                   hipMemcpyDeviceToDevice, stream);

    proj_t_kernel<<<dim3(N_ / 64, C_ / 64, B_), 256, 0, stream>>>(x_s2, Wq, bq, Qt, C_, 1.0f);
    proj_t_kernel<<<dim3(N_ / 64, C_ / 64, B_), 256, 0, stream>>>(x_dem, Wk, bk, Kt, CD_, SCALE_LOG2E);
    proj_n_kernel<<<dim3(N_ / 64, C_ / 64, B_), 256, 0, stream>>>(x_dem, Wv, bv, Vm, CD_);
    stats_kernel<<<dim3(N_ / 128, N_ / 128, B_), 256, 0, stream>>>(Kt, Qt, lv);
    out_kernel<<<dim3(N_ / 64, 4, B_), 512, 0, stream>>>(Kt, Qt, Vm, lv, out);
}

// Round 4
// 378.346 us; speedup vs baseline: 1.2023x; 1.2023x over previous
//
#include <hip/hip_runtime.h>
#include <hip/hip_bf16.h>
#include <cstdint>

#define B_  4
#define N_  4096
#define C_  256
#define CD_ 64

typedef unsigned short ushort_t;
typedef __bf16 bf16x8 __attribute__((ext_vector_type(8)));
typedef float f32x4 __attribute__((ext_vector_type(4)));

typedef const __attribute__((address_space(1))) void* gas_t;
typedef __attribute__((address_space(3))) void* las_t;

// (1/sqrt(256)) * log2(e): folded into K projection so S' = S_true * log2(e)
static constexpr float SCALE_LOG2E = 0.09016844005556021f;

__device__ __forceinline__ ushort_t f2bf(float x) {
    union { float f; unsigned u; } v; v.f = x;
    unsigned u = v.u;
    unsigned r = (u + 0x7fffu + ((u >> 16) & 1u)) >> 16;  // round-nearest-even
    return (ushort_t)r;
}

__device__ __forceinline__ bf16x8 ld_bf8(const ushort_t* p) {
    return *reinterpret_cast<const bf16x8*>(p);
}

// ---------------------------------------------------------------------------
// Projection producing TRANSPOSED bf16 output dst[b][n][o]  (for Qt, Kt)
// dst = (W @ X + bias) * outScale      (unchanged — proven correct)
// ---------------------------------------------------------------------------
__global__ void proj_t_kernel(const float* __restrict__ X, const float* __restrict__ W,
                              const float* __restrict__ bias, ushort_t* __restrict__ dst,
                              int Cin, float outScale) {
    __shared__ float sX[16][68];
    __shared__ float sW[64][17];
    const int tid = threadIdx.x;
    const int b = blockIdx.z;
    const int oBase = blockIdx.y * 64;
    const int nBase = blockIdx.x * 64;
    const int tx = tid & 15, ty = tid >> 4;
    float acc[4][4] = {};
    for (int k0 = 0; k0 < Cin; k0 += 16) {
        int kk = tid >> 4, nn = (tid & 15) * 4;
        float4 xv = *(const float4*)(X + ((size_t)b * Cin + k0 + kk) * N_ + nBase + nn);
        *(float4*)&sX[kk][nn] = xv;
        int oo = tid >> 2, kc = (tid & 3) * 4;
        float4 wv = *(const float4*)(W + (size_t)(oBase + oo) * Cin + k0 + kc);
        sW[oo][kc + 0] = wv.x; sW[oo][kc + 1] = wv.y;
        sW[oo][kc + 2] = wv.z; sW[oo][kc + 3] = wv.w;
        __syncthreads();
#pragma unroll
        for (int kk2 = 0; kk2 < 16; ++kk2) {
            float4 xr4 = *(float4*)&sX[kk2][tx * 4];
            float xr[4] = {xr4.x, xr4.y, xr4.z, xr4.w};
#pragma unroll
            for (int i = 0; i < 4; ++i) {
                float wv2 = sW[ty * 4 + i][kk2];
#pragma unroll
                for (int j = 0; j < 4; ++j) acc[i][j] += wv2 * xr[j];
            }
        }
        __syncthreads();
    }
    float4 bi4 = *(const float4*)(bias + oBase + ty * 4);
    float bia[4] = {bi4.x, bi4.y, bi4.z, bi4.w};
#pragma unroll
    for (int j = 0; j < 4; ++j) {
        int n = nBase + tx * 4 + j;
        unsigned p0 = f2bf((acc[0][j] + bia[0]) * outScale);
        unsigned p1 = f2bf((acc[1][j] + bia[1]) * outScale);
        unsigned p2 = f2bf((acc[2][j] + bia[2]) * outScale);
        unsigned p3 = f2bf((acc[3][j] + bia[3]) * outScale);
        uint2 pk; pk.x = p0 | (p1 << 16); pk.y = p2 | (p3 << 16);
        *(uint2*)(dst + ((size_t)b * N_ + n) * C_ + oBase + ty * 4) = pk;
    }
}

// ---------------------------------------------------------------------------
// Projection producing NATURAL bf16 output dst[b][o][n]  (for V) — unchanged
// ---------------------------------------------------------------------------
__global__ void proj_n_kernel(const float* __restrict__ X, const float* __restrict__ W,
                              const float* __restrict__ bias, ushort_t* __restrict__ dst,
                              int Cin) {
    __shared__ float sX[16][68];
    __shared__ float sW[64][17];
    const int tid = threadIdx.x;
    const int b = blockIdx.z;
    const int oBase = blockIdx.y * 64;
    const int nBase = blockIdx.x * 64;
    const int tx = tid & 15, ty = tid >> 4;
    float acc[4][4] = {};
    for (int k0 = 0; k0 < Cin; k0 += 16) {
        int kk = tid >> 4, nn = (tid & 15) * 4;
        float4 xv = *(const float4*)(X + ((size_t)b * Cin + k0 + kk) * N_ + nBase + nn);
        *(float4*)&sX[kk][nn] = xv;
        int oo = tid >> 2, kc = (tid & 3) * 4;
        float4 wv = *(const float4*)(W + (size_t)(oBase + oo) * Cin + k0 + kc);
        sW[oo][kc + 0] = wv.x; sW[oo][kc + 1] = wv.y;
        sW[oo][kc + 2] = wv.z; sW[oo][kc + 3] = wv.w;
        __syncthreads();
#pragma unroll
        for (int kk2 = 0; kk2 < 16; ++kk2) {
            float4 xr4 = *(float4*)&sX[kk2][tx * 4];
            float xr[4] = {xr4.x, xr4.y, xr4.z, xr4.w};
#pragma unroll
            for (int i = 0; i < 4; ++i) {
                float wv2 = sW[ty * 4 + i][kk2];
#pragma unroll
                for (int j = 0; j < 4; ++j) acc[i][j] += wv2 * xr[j];
            }
        }
        __syncthreads();
    }
#pragma unroll
    for (int i = 0; i < 4; ++i) {
        int o = oBase + ty * 4 + i;
        float bia = bias[o];
        unsigned p0 = f2bf(acc[i][0] + bia);
        unsigned p1 = f2bf(acc[i][1] + bia);
        unsigned p2 = f2bf(acc[i][2] + bia);
        unsigned p3 = f2bf(acc[i][3] + bia);
        uint2 pk; pk.x = p0 | (p1 << 16); pk.y = p2 | (p3 << 16);
        *(uint2*)(dst + ((size_t)b * C_ + o) * N_ + nBase + tx * 4) = pk;
    }
}

// ---------------------------------------------------------------------------
// Pass A: l[b][i] = sum_j exp2(S'[i][j]).  m97-style GEMM, 128x128 tile,
// BK=64, global_load_lds(16B) with XOR-swizzled source chunks. (unchanged)
// ---------------------------------------------------------------------------
__global__ __launch_bounds__(256, 5)
void stats_kernel(const ushort_t* __restrict__ Kt, const ushort_t* __restrict__ Qt,
                  float* __restrict__ l) {
    __shared__ ushort_t sA[128 * 64];
    __shared__ ushort_t sB[128 * 64];
    const int tid = threadIdx.x;
    const int lane = tid & 63, g = lane >> 4, c16 = lane & 15;
    const int w = tid >> 6, wi = w >> 1, wj = w & 1;
    const int b = blockIdx.z;
    const int ib = blockIdx.y * 128, jb = blockIdx.x * 128;
    f32x4 acc[4][4];
#pragma unroll
    for (int mt = 0; mt < 4; ++mt)
#pragma unroll
        for (int nt = 0; nt < 4; ++nt) acc[mt][nt] = (f32x4){0.f, 0.f, 0.f, 0.f};

    const int srow = tid >> 3;
    const int sc4 = tid & 7;

    for (int k0 = 0; k0 < 256; k0 += 64) {
#pragma unroll
        for (int q = 0; q < 4; ++q) {
            const int row = q * 32 + srow;
            const int gc = sc4 ^ (row & 7);
            const ushort_t* srcA = Kt + ((size_t)(b * N_ + ib + row)) * C_ + k0 + gc * 8;
            const ushort_t* srcB = Qt + ((size_t)(b * N_ + jb + row)) * C_ + k0 + gc * 8;
            __builtin_amdgcn_global_load_lds((gas_t)srcA, (las_t)&sA[(q * 256 + tid) * 8], 16, 0, 0);
            __builtin_amdgcn_global_load_lds((gas_t)srcB, (las_t)&sB[(q * 256 + tid) * 8], 16, 0, 0);
        }
        __syncthreads();
#pragma unroll
        for (int ks = 0; ks < 2; ++ks) {
            bf16x8 af[4], bf[4];
#pragma unroll
            for (int mt = 0; mt < 4; ++mt) {
                const int row = wi * 64 + mt * 16 + c16;
                af[mt] = *(const bf16x8*)&sA[row * 64 + (((ks * 4 + g) ^ (row & 7)) * 8)];
            }
#pragma unroll
            for (int nt = 0; nt < 4; ++nt) {
                const int row = wj * 64 + nt * 16 + c16;
                bf[nt] = *(const bf16x8*)&sB[row * 64 + (((ks * 4 + g) ^ (row & 7)) * 8)];
            }
#pragma unroll
            for (int mt = 0; mt < 4; ++mt)
#pragma unroll
                for (int nt = 0; nt < 4; ++nt)
                    acc[mt][nt] = __builtin_amdgcn_mfma_f32_16x16x32_bf16(af[mt], bf[nt], acc[mt][nt], 0, 0, 0);
        }
        __syncthreads();
    }
#pragma unroll
    for (int mt = 0; mt < 4; ++mt) {
#pragma unroll
        for (int r = 0; r < 4; ++r) {
            float s = __builtin_amdgcn_exp2f(acc[mt][0][r]) + __builtin_amdgcn_exp2f(acc[mt][1][r])
                    + __builtin_amdgcn_exp2f(acc[mt][2][r]) + __builtin_amdgcn_exp2f(acc[mt][3][r]);
            s += __shfl_xor(s, 1, 64);
            s += __shfl_xor(s, 2, 64);
            s += __shfl_xor(s, 4, 64);
            s += __shfl_xor(s, 8, 64);
            if (c16 == 0)
                atomicAdd(l + (size_t)b * N_ + ib + wi * 64 + mt * 16 + g * 4 + r, s);
        }
    }
}

// ---------------------------------------------------------------------------
// Pass B v4: O[c][j] += sum_i V[c][i] * exp2(S'[i][j] - log2 l_i).
// R2 shape (i-split 2, atomic fan-in 2 — R3 proved 4-way atomics ping-pong
// across XCDs: WRITE 32->399 MB) but i-chunk 256 with 2x4 S-blocking:
//   S phase : wave w owns i-band w*32..+32 (mt2) x all 64 j (nt4), K=256.
//             A-frag (Kt, global) reused over nt4; B-frag (sQ) over mt2.
//             -> sQ LDS bytes per i halved vs R2; barriers per i halved.
//   PV phase: wave w owns c-band w*32..+32 (mt2) x all 64 j (nt4), ks=8.
// Per wave per chunk: 128 MFMA / 32 gl b128 / 64 LDS b128 (R2: 128/32/96).
// exp2/log2 via raw builtins (libm exp2f is ~8 instrs; tail VALU halves).
// grid (64 j-tiles, 2 i-halves, B), block 512.
// ---------------------------------------------------------------------------
__global__ __launch_bounds__(512, 4)
void out_kernel(const ushort_t* __restrict__ Kt, const ushort_t* __restrict__ Qt,
                const ushort_t* __restrict__ V, const float* __restrict__ l,
                float* __restrict__ dout) {
    __shared__ ushort_t sQ[64][264];   // Qt j-tile [jloc][c], +8 pad (33 KB)
    __shared__ ushort_t sP[64][264];   // P^T [jloc][iloc 0..256], +8 pad (33 KB)
    const int tid = threadIdx.x;
    const int w = tid >> 6, lane = tid & 63, g = lane >> 4, c16 = lane & 15;
    const int b = blockIdx.z;
    const int jb = blockIdx.x * 64;
    const int ibase = blockIdx.y * 2048;

    // stage Qt j-tile once (padded rows; regular stores)
    {
        const int jl = tid >> 3, cp = (tid & 7) * 32;
        const ushort_t* src = Qt + ((size_t)(b * N_ + jb + jl)) * C_ + cp;
        uint4 a0 = *(const uint4*)(src);
        uint4 a1 = *(const uint4*)(src + 8);
        uint4 a2 = *(const uint4*)(src + 16);
        uint4 a3 = *(const uint4*)(src + 24);
        *(uint4*)&sQ[jl][cp + 0]  = a0;
        *(uint4*)&sQ[jl][cp + 8]  = a1;
        *(uint4*)&sQ[jl][cp + 16] = a2;
        *(uint4*)&sQ[jl][cp + 24] = a3;
    }
    f32x4 acc[2][4];
#pragma unroll
    for (int mt = 0; mt < 2; ++mt)
#pragma unroll
        for (int nt = 0; nt < 4; ++nt) acc[mt][nt] = (f32x4){0.f, 0.f, 0.f, 0.f};

    const int bw = w * 32;    // wave band: S-phase i rows / PV-phase c rows

    for (int ic = 0; ic < 8; ++ic) {
        const int i0 = ibase + ic * 256;
        // l for this wave's 32 i rows (independent of LDS; completes at barrier)
        float rv[2][4];
#pragma unroll
        for (int mt = 0; mt < 2; ++mt) {
            float4 lr = *(const float4*)(l + (size_t)b * N_ + i0 + bw + mt * 16 + g * 4);
            rv[mt][0] = __builtin_amdgcn_logf(lr.x);
            rv[mt][1] = __builtin_amdgcn_logf(lr.y);
            rv[mt][2] = __builtin_amdgcn_logf(lr.z);
            rv[mt][3] = __builtin_amdgcn_logf(lr.w);
        }
        __syncthreads();   // barrier A: prev chunk's PV done -> sP writable
        // ---- S phase: 32 i x 64 j, K=256 ----
        f32x4 sa[2][4];
#pragma unroll
        for (int mt = 0; mt < 2; ++mt)
#pragma unroll
            for (int nt = 0; nt < 4; ++nt) sa[mt][nt] = (f32x4){0.f, 0.f, 0.f, 0.f};
#pragma unroll
        for (int k = 0; k < 8; ++k) {
            bf16x8 av[2];
#pragma unroll
            for (int mt = 0; mt < 2; ++mt)
                av[mt] = ld_bf8(Kt + ((size_t)(b * N_ + i0 + bw + mt * 16 + c16)) * C_ + k * 32 + g * 8);
#pragma unroll
            for (int nt = 0; nt < 4; ++nt) {
                bf16x8 bv = *(const bf16x8*)&sQ[nt * 16 + c16][k * 32 + g * 8];
#pragma unroll
                for (int mt = 0; mt < 2; ++mt)
                    sa[mt][nt] = __builtin_amdgcn_mfma_f32_16x16x32_bf16(av[mt], bv, sa[mt][nt], 0, 0, 0);
            }
        }
#pragma unroll
        for (int mt = 0; mt < 2; ++mt)
#pragma unroll
            for (int nt = 0; nt < 4; ++nt) {
                const int j = nt * 16 + c16;
                unsigned p0 = f2bf(__builtin_amdgcn_exp2f(sa[mt][nt][0] - rv[mt][0]));
                unsigned p1 = f2bf(__builtin_amdgcn_exp2f(sa[mt][nt][1] - rv[mt][1]));
                unsigned p2 = f2bf(__builtin_amdgcn_exp2f(sa[mt][nt][2] - rv[mt][2]));
                unsigned p3 = f2bf(__builtin_amdgcn_exp2f(sa[mt][nt][3] - rv[mt][3]));
                uint2 pk; pk.x = p0 | (p1 << 16); pk.y = p2 | (p3 << 16);
                *(uint2*)&sP[j][bw + mt * 16 + g * 4] = pk;
            }
        __syncthreads();   // barrier B: sP ready
        // ---- PV phase: 32 c x 64 j, K = 256 i ----
#pragma unroll
        for (int ks = 0; ks < 8; ++ks) {
            bf16x8 va[2];
#pragma unroll
            for (int mt = 0; mt < 2; ++mt)
                va[mt] = ld_bf8(V + ((size_t)(b * C_ + bw + mt * 16 + c16)) * N_ + i0 + ks * 32 + g * 8);
#pragma unroll
            for (int nt = 0; nt < 4; ++nt) {
                bf16x8 pb = *(const bf16x8*)&sP[nt * 16 + c16][ks * 32 + g * 8];
#pragma unroll
                for (int mt = 0; mt < 2; ++mt)
                    acc[mt][nt] = __builtin_amdgcn_mfma_f32_16x16x32_bf16(va[mt], pb, acc[mt][nt], 0, 0, 0);
            }
        }
    }
#pragma unroll
    for (int mt = 0; mt < 2; ++mt)
#pragma unroll
        for (int nt = 0; nt < 4; ++nt)
#pragma unroll
            for (int r = 0; r < 4; ++r) {
                const int c = bw + mt * 16 + g * 4 + r;
                const int j = jb + nt * 16 + c16;
                atomicAdd(dout + ((size_t)b * C_ + c) * N_ + j, acc[mt][nt][r]);
            }
}

extern "C" void kernel_launch(void* const* d_in, const int* in_sizes, int n_in,
                              void* d_out, int out_size, void* d_ws, size_t ws_size,
                              hipStream_t stream) {
    const float* x_s2  = (const float*)d_in[0];
    const float* x_dem = (const float*)d_in[1];
    const float* Wq = (const float*)d_in[2];
    const float* bq = (const float*)d_in[3];
    const float* Wk = (const float*)d_in[4];
    const float* bk = (const float*)d_in[5];
    const float* Wv = (const float*)d_in[6];
    const float* bv = (const float*)d_in[7];
    float* out = (float*)d_out;

    char* ws = (char*)d_ws;
    ushort_t* Qt = (ushort_t*)(ws);                               // [B][N][C] bf16, 8 MB
    ushort_t* Kt = (ushort_t*)(ws + (size_t)8  * 1024 * 1024);    // [B][N][C] bf16, pre-scaled
    ushort_t* Vm = (ushort_t*)(ws + (size_t)16 * 1024 * 1024);    // [B][C][N] bf16
    float*    lv = (float*)   (ws + (size_t)24 * 1024 * 1024);    // [B][N] row sums

    hipMemsetAsync(lv, 0, (size_t)B_ * N_ * sizeof(float), stream);
    // residual: pre-fill output with x_s2; out_kernel atomically adds O
    hipMemcpyAsync(out, x_s2, (size_t)B_ * C_ * N_ * sizeof(float),
                   hipMemcpyDeviceToDevice, stream);

    proj_t_kernel<<<dim3(N_ / 64, C_ / 64, B_), 256, 0, stream>>>(x_s2, Wq, bq, Qt, C_, 1.0f);
    proj_t_kernel<<<dim3(N_ / 64, C_ / 64, B_), 256, 0, stream>>>(x_dem, Wk, bk, Kt, CD_, SCALE_LOG2E);
    proj_n_kernel<<<dim3(N_ / 64, C_ / 64, B_), 256, 0, stream>>>(x_dem, Wv, bv, Vm, CD_);
    stats_kernel<<<dim3(N_ / 128, N_ / 128, B_), 256, 0, stream>>>(Kt, Qt, lv);
    out_kernel<<<dim3(N_ / 64, 2, B_), 512, 0, stream>>>(Kt, Qt, Vm, lv, out);
}

// Round 5
// 287.431 us; speedup vs baseline: 1.5826x; 1.3163x over previous
//
#include <hip/hip_runtime.h>
#include <hip/hip_bf16.h>
#include <cstdint>

#define B_  4
#define N_  4096
#define C_  256
#define CD_ 64

typedef unsigned short ushort_t;
typedef __bf16 bf16x8 __attribute__((ext_vector_type(8)));
typedef float f32x4 __attribute__((ext_vector_type(4)));

typedef const __attribute__((address_space(1))) void* gas_t;
typedef __attribute__((address_space(3))) void* las_t;

// (1/sqrt(256)) * log2(e): folded into K projection so S' = S_true * log2(e)
static constexpr float SCALE_LOG2E = 0.09016844005556021f;

__device__ __forceinline__ ushort_t f2bf(float x) {
    union { float f; unsigned u; } v; v.f = x;
    unsigned u = v.u;
    unsigned r = (u + 0x7fffu + ((u >> 16) & 1u)) >> 16;  // round-nearest-even
    return (ushort_t)r;
}

__device__ __forceinline__ bf16x8 ld_bf8(const ushort_t* p) {
    return *reinterpret_cast<const bf16x8*>(p);
}

// ---------------------------------------------------------------------------
// Projection producing TRANSPOSED bf16 output dst[b][n][o]  (for Qt, Kt)
// dst = (W @ X + bias) * outScale      (unchanged — proven correct)
// ---------------------------------------------------------------------------
__global__ void proj_t_kernel(const float* __restrict__ X, const float* __restrict__ W,
                              const float* __restrict__ bias, ushort_t* __restrict__ dst,
                              int Cin, float outScale) {
    __shared__ float sX[16][68];
    __shared__ float sW[64][17];
    const int tid = threadIdx.x;
    const int b = blockIdx.z;
    const int oBase = blockIdx.y * 64;
    const int nBase = blockIdx.x * 64;
    const int tx = tid & 15, ty = tid >> 4;
    float acc[4][4] = {};
    for (int k0 = 0; k0 < Cin; k0 += 16) {
        int kk = tid >> 4, nn = (tid & 15) * 4;
        float4 xv = *(const float4*)(X + ((size_t)b * Cin + k0 + kk) * N_ + nBase + nn);
        *(float4*)&sX[kk][nn] = xv;
        int oo = tid >> 2, kc = (tid & 3) * 4;
        float4 wv = *(const float4*)(W + (size_t)(oBase + oo) * Cin + k0 + kc);
        sW[oo][kc + 0] = wv.x; sW[oo][kc + 1] = wv.y;
        sW[oo][kc + 2] = wv.z; sW[oo][kc + 3] = wv.w;
        __syncthreads();
#pragma unroll
        for (int kk2 = 0; kk2 < 16; ++kk2) {
            float4 xr4 = *(float4*)&sX[kk2][tx * 4];
            float xr[4] = {xr4.x, xr4.y, xr4.z, xr4.w};
#pragma unroll
            for (int i = 0; i < 4; ++i) {
                float wv2 = sW[ty * 4 + i][kk2];
#pragma unroll
                for (int j = 0; j < 4; ++j) acc[i][j] += wv2 * xr[j];
            }
        }
        __syncthreads();
    }
    float4 bi4 = *(const float4*)(bias + oBase + ty * 4);
    float bia[4] = {bi4.x, bi4.y, bi4.z, bi4.w};
#pragma unroll
    for (int j = 0; j < 4; ++j) {
        int n = nBase + tx * 4 + j;
        unsigned p0 = f2bf((acc[0][j] + bia[0]) * outScale);
        unsigned p1 = f2bf((acc[1][j] + bia[1]) * outScale);
        unsigned p2 = f2bf((acc[2][j] + bia[2]) * outScale);
        unsigned p3 = f2bf((acc[3][j] + bia[3]) * outScale);
        uint2 pk; pk.x = p0 | (p1 << 16); pk.y = p2 | (p3 << 16);
        *(uint2*)(dst + ((size_t)b * N_ + n) * C_ + oBase + ty * 4) = pk;
    }
}

// ---------------------------------------------------------------------------
// Projection producing NATURAL bf16 output dst[b][o][n]  (for V) — unchanged
// ---------------------------------------------------------------------------
__global__ void proj_n_kernel(const float* __restrict__ X, const float* __restrict__ W,
                              const float* __restrict__ bias, ushort_t* __restrict__ dst,
                              int Cin) {
    __shared__ float sX[16][68];
    __shared__ float sW[64][17];
    const int tid = threadIdx.x;
    const int b = blockIdx.z;
    const int oBase = blockIdx.y * 64;
    const int nBase = blockIdx.x * 64;
    const int tx = tid & 15, ty = tid >> 4;
    float acc[4][4] = {};
    for (int k0 = 0; k0 < Cin; k0 += 16) {
        int kk = tid >> 4, nn = (tid & 15) * 4;
        float4 xv = *(const float4*)(X + ((size_t)b * Cin + k0 + kk) * N_ + nBase + nn);
        *(float4*)&sX[kk][nn] = xv;
        int oo = tid >> 2, kc = (tid & 3) * 4;
        float4 wv = *(const float4*)(W + (size_t)(oBase + oo) * Cin + k0 + kc);
        sW[oo][kc + 0] = wv.x; sW[oo][kc + 1] = wv.y;
        sW[oo][kc + 2] = wv.z; sW[oo][kc + 3] = wv.w;
        __syncthreads();
#pragma unroll
        for (int kk2 = 0; kk2 < 16; ++kk2) {
            float4 xr4 = *(float4*)&sX[kk2][tx * 4];
            float xr[4] = {xr4.x, xr4.y, xr4.z, xr4.w};
#pragma unroll
            for (int i = 0; i < 4; ++i) {
                float wv2 = sW[ty * 4 + i][kk2];
#pragma unroll
                for (int j = 0; j < 4; ++j) acc[i][j] += wv2 * xr[j];
            }
        }
        __syncthreads();
    }
#pragma unroll
    for (int i = 0; i < 4; ++i) {
        int o = oBase + ty * 4 + i;
        float bia = bias[o];
        unsigned p0 = f2bf(acc[i][0] + bia);
        unsigned p1 = f2bf(acc[i][1] + bia);
        unsigned p2 = f2bf(acc[i][2] + bia);
        unsigned p3 = f2bf(acc[i][3] + bia);
        uint2 pk; pk.x = p0 | (p1 << 16); pk.y = p2 | (p3 << 16);
        *(uint2*)(dst + ((size_t)b * C_ + o) * N_ + nBase + tx * 4) = pk;
    }
}

// ---------------------------------------------------------------------------
// Pass A v3: l[b][i] = sum_j exp2(S'[i][j]), and (if PT != null) store
// P^T[j][i] = exp2(S'[i][j]) as bf16 (unnormalized; 1/l folds into V later).
// m97-style GEMM, 128x128 tile, BK=64, global_load_lds(16B) + XOR swizzle.
// launch_bounds back to (256,3): R3's (256,5) coincided with +19 us on the
// non-out remainder.
// ---------------------------------------------------------------------------
__global__ __launch_bounds__(256, 3)
void stats_kernel(const ushort_t* __restrict__ Kt, const ushort_t* __restrict__ Qt,
                  float* __restrict__ l, ushort_t* __restrict__ PT) {
    __shared__ ushort_t sA[128 * 64];
    __shared__ ushort_t sB[128 * 64];
    const int tid = threadIdx.x;
    const int lane = tid & 63, g = lane >> 4, c16 = lane & 15;
    const int w = tid >> 6, wi = w >> 1, wj = w & 1;
    const int b = blockIdx.z;
    const int ib = blockIdx.y * 128, jb = blockIdx.x * 128;
    f32x4 acc[4][4];
#pragma unroll
    for (int mt = 0; mt < 4; ++mt)
#pragma unroll
        for (int nt = 0; nt < 4; ++nt) acc[mt][nt] = (f32x4){0.f, 0.f, 0.f, 0.f};

    const int srow = tid >> 3;
    const int sc4 = tid & 7;

    for (int k0 = 0; k0 < 256; k0 += 64) {
#pragma unroll
        for (int q = 0; q < 4; ++q) {
            const int row = q * 32 + srow;
            const int gc = sc4 ^ (row & 7);
            const ushort_t* srcA = Kt + ((size_t)(b * N_ + ib + row)) * C_ + k0 + gc * 8;
            const ushort_t* srcB = Qt + ((size_t)(b * N_ + jb + row)) * C_ + k0 + gc * 8;
            __builtin_amdgcn_global_load_lds((gas_t)srcA, (las_t)&sA[(q * 256 + tid) * 8], 16, 0, 0);
            __builtin_amdgcn_global_load_lds((gas_t)srcB, (las_t)&sB[(q * 256 + tid) * 8], 16, 0, 0);
        }
        __syncthreads();
#pragma unroll
        for (int ks = 0; ks < 2; ++ks) {
            bf16x8 af[4], bf[4];
#pragma unroll
            for (int mt = 0; mt < 4; ++mt) {
                const int row = wi * 64 + mt * 16 + c16;
                af[mt] = *(const bf16x8*)&sA[row * 64 + (((ks * 4 + g) ^ (row & 7)) * 8)];
            }
#pragma unroll
            for (int nt = 0; nt < 4; ++nt) {
                const int row = wj * 64 + nt * 16 + c16;
                bf[nt] = *(const bf16x8*)&sB[row * 64 + (((ks * 4 + g) ^ (row & 7)) * 8)];
            }
#pragma unroll
            for (int mt = 0; mt < 4; ++mt)
#pragma unroll
                for (int nt = 0; nt < 4; ++nt)
                    acc[mt][nt] = __builtin_amdgcn_mfma_f32_16x16x32_bf16(af[mt], bf[nt], acc[mt][nt], 0, 0, 0);
        }
        __syncthreads();
    }
    // epilogue: e = exp2(S'); optional P^T store; row-sum over this block's
    // 128 j; atomic into l.  Element (i,j): i = ib+wi*64+mt*16+g*4+r,
    // j = jb+wj*64+nt*16+c16 (verified C/D mapping, absmax-proven R1-R4).
#pragma unroll
    for (int mt = 0; mt < 4; ++mt) {
        float rs[4] = {0.f, 0.f, 0.f, 0.f};
#pragma unroll
        for (int nt = 0; nt < 4; ++nt) {
            float e0 = __builtin_amdgcn_exp2f(acc[mt][nt][0]);
            float e1 = __builtin_amdgcn_exp2f(acc[mt][nt][1]);
            float e2 = __builtin_amdgcn_exp2f(acc[mt][nt][2]);
            float e3 = __builtin_amdgcn_exp2f(acc[mt][nt][3]);
            rs[0] += e0; rs[1] += e1; rs[2] += e2; rs[3] += e3;
            if (PT != nullptr) {
                uint2 pk;
                pk.x = (unsigned)f2bf(e0) | ((unsigned)f2bf(e1) << 16);
                pk.y = (unsigned)f2bf(e2) | ((unsigned)f2bf(e3) << 16);
                const int j = jb + wj * 64 + nt * 16 + c16;
                const int i = ib + wi * 64 + mt * 16 + g * 4;
                *(uint2*)(PT + ((size_t)b * N_ + j) * N_ + i) = pk;
            }
        }
#pragma unroll
        for (int r = 0; r < 4; ++r) {
            float s = rs[r];
            s += __shfl_xor(s, 1, 64);
            s += __shfl_xor(s, 2, 64);
            s += __shfl_xor(s, 4, 64);
            s += __shfl_xor(s, 8, 64);
            if (c16 == 0)
                atomicAdd(l + (size_t)b * N_ + ib + wi * 64 + mt * 16 + g * 4 + r, s);
        }
    }
}

// ---------------------------------------------------------------------------
// V' = V * rcp(l) elementwise.  grid (N/2048, C, B), block 256, 8 elems/thr.
// ---------------------------------------------------------------------------
__global__ void scale_v_kernel(const ushort_t* __restrict__ Vm, const float* __restrict__ l,
                               ushort_t* __restrict__ Vs) {
    const int i = (blockIdx.x * 256 + threadIdx.x) * 8;
    const int c = blockIdx.y, b = blockIdx.z;
    float4 l0 = *(const float4*)(l + (size_t)b * N_ + i);
    float4 l1 = *(const float4*)(l + (size_t)b * N_ + i + 4);
    float r[8] = {__builtin_amdgcn_rcpf(l0.x), __builtin_amdgcn_rcpf(l0.y),
                  __builtin_amdgcn_rcpf(l0.z), __builtin_amdgcn_rcpf(l0.w),
                  __builtin_amdgcn_rcpf(l1.x), __builtin_amdgcn_rcpf(l1.y),
                  __builtin_amdgcn_rcpf(l1.z), __builtin_amdgcn_rcpf(l1.w)};
    const size_t off = ((size_t)(b * C_ + c)) * N_ + i;
    uint4 v = *(const uint4*)(Vm + off);
    unsigned vw[4] = {v.x, v.y, v.z, v.w};
    uint4 o;
    unsigned* ow = &o.x;
#pragma unroll
    for (int q = 0; q < 4; ++q) {
        union { unsigned u; float f; } lo, hi;
        lo.u = (vw[q] & 0xffffu) << 16;
        hi.u = vw[q] & 0xffff0000u;
        float f0 = lo.f * r[q * 2 + 0];
        float f1 = hi.f * r[q * 2 + 1];
        ow[q] = (unsigned)f2bf(f0) | ((unsigned)f2bf(f1) << 16);
    }
    *(uint4*)(Vs + off) = o;
}

// ---------------------------------------------------------------------------
// Pass B v5: pure GEMM  O[c][j] = sum_i V'[c][i] * PT[j][i], K-split 2
// (atomic fan-in 2 onto residual-prefilled d_out — R2-proven; fan-in 4 is
// not, R3).  m97 structure: 128x128 tile, BK=64, global_load_lds(16B) + XOR
// swizzle.  grid (32 j, 2 ct x 2 kh, B), block 512 (8 waves, 4c x 2j).
// ---------------------------------------------------------------------------
__global__ __launch_bounds__(512, 4)
void gemm_out_kernel(const ushort_t* __restrict__ A /*V'*/, const ushort_t* __restrict__ Bm /*PT*/,
                     float* __restrict__ dout) {
    __shared__ ushort_t sA[128 * 64];
    __shared__ ushort_t sB[128 * 64];
    const int tid = threadIdx.x;
    const int lane = tid & 63, g = lane >> 4, c16 = lane & 15;
    const int w = tid >> 6;
    const int cw = (w & 3) * 32, jw = (w >> 2) * 64;
    const int b = blockIdx.z;
    const int jb = blockIdx.x * 128;
    const int ct = (blockIdx.y & 1) * 128;
    const int kh = (blockIdx.y >> 1) * 2048;

    f32x4 acc[2][4];
#pragma unroll
    for (int mt = 0; mt < 2; ++mt)
#pragma unroll
        for (int nt = 0; nt < 4; ++nt) acc[mt][nt] = (f32x4){0.f, 0.f, 0.f, 0.f};

    const int srow = tid >> 3;   // 0..63; q adds 64
    const int sc8 = tid & 7;

    for (int k0 = 0; k0 < 2048; k0 += 64) {
#pragma unroll
        for (int q = 0; q < 2; ++q) {
            const int row = q * 64 + srow;
            const int gc = sc8 ^ (row & 7);
            const ushort_t* srcA = A + ((size_t)(b * C_ + ct + row)) * N_ + kh + k0 + gc * 8;
            const ushort_t* srcB = Bm + ((size_t)(b * N_ + jb + row)) * N_ + kh + k0 + gc * 8;
            __builtin_amdgcn_global_load_lds((gas_t)srcA, (las_t)&sA[(q * 512 + tid) * 8], 16, 0, 0);
            __builtin_amdgcn_global_load_lds((gas_t)srcB, (las_t)&sB[(q * 512 + tid) * 8], 16, 0, 0);
        }
        __syncthreads();
#pragma unroll
        for (int ks = 0; ks < 2; ++ks) {
            bf16x8 af[2], bfg[4];
#pragma unroll
            for (int mt = 0; mt < 2; ++mt) {
                const int row = cw + mt * 16 + c16;
                af[mt] = *(const bf16x8*)&sA[row * 64 + (((ks * 4 + g) ^ (row & 7)) * 8)];
            }
#pragma unroll
            for (int nt = 0; nt < 4; ++nt) {
                const int row = jw + nt * 16 + c16;
                bfg[nt] = *(const bf16x8*)&sB[row * 64 + (((ks * 4 + g) ^ (row & 7)) * 8)];
            }
#pragma unroll
            for (int mt = 0; mt < 2; ++mt)
#pragma unroll
                for (int nt = 0; nt < 4; ++nt)
                    acc[mt][nt] = __builtin_amdgcn_mfma_f32_16x16x32_bf16(af[mt], bfg[nt], acc[mt][nt], 0, 0, 0);
        }
        __syncthreads();
    }
#pragma unroll
    for (int mt = 0; mt < 2; ++mt)
#pragma unroll
        for (int nt = 0; nt < 4; ++nt)
#pragma unroll
            for (int r = 0; r < 4; ++r) {
                const int c = ct + cw + mt * 16 + g * 4 + r;
                const int j = jb + jw + nt * 16 + c16;
                atomicAdd(dout + ((size_t)b * C_ + c) * N_ + j, acc[mt][nt][r]);
            }
}

// ---------------------------------------------------------------------------
// Fallback Pass B (R4, proven 153 us) — used when ws_size < 161 MiB.
// ---------------------------------------------------------------------------
__global__ __launch_bounds__(512, 4)
void out_kernel(const ushort_t* __restrict__ Kt, const ushort_t* __restrict__ Qt,
                const ushort_t* __restrict__ V, const float* __restrict__ l,
                float* __restrict__ dout) {
    __shared__ ushort_t sQ[64][264];
    __shared__ ushort_t sP[64][264];
    const int tid = threadIdx.x;
    const int w = tid >> 6, lane = tid & 63, g = lane >> 4, c16 = lane & 15;
    const int b = blockIdx.z;
    const int jb = blockIdx.x * 64;
    const int ibase = blockIdx.y * 2048;
    {
        const int jl = tid >> 3, cp = (tid & 7) * 32;
        const ushort_t* src = Qt + ((size_t)(b * N_ + jb + jl)) * C_ + cp;
        uint4 a0 = *(const uint4*)(src);
        uint4 a1 = *(const uint4*)(src + 8);
        uint4 a2 = *(const uint4*)(src + 16);
        uint4 a3 = *(const uint4*)(src + 24);
        *(uint4*)&sQ[jl][cp + 0]  = a0;
        *(uint4*)&sQ[jl][cp + 8]  = a1;
        *(uint4*)&sQ[jl][cp + 16] = a2;
        *(uint4*)&sQ[jl][cp + 24] = a3;
    }
    f32x4 acc[2][4];
#pragma unroll
    for (int mt = 0; mt < 2; ++mt)
#pragma unroll
        for (int nt = 0; nt < 4; ++nt) acc[mt][nt] = (f32x4){0.f, 0.f, 0.f, 0.f};

    const int bw = w * 32;

    for (int ic = 0; ic < 8; ++ic) {
        const int i0 = ibase + ic * 256;
        float rv[2][4];
#pragma unroll
        for (int mt = 0; mt < 2; ++mt) {
            float4 lr = *(const float4*)(l + (size_t)b * N_ + i0 + bw + mt * 16 + g * 4);
            rv[mt][0] = __builtin_amdgcn_logf(lr.x);
            rv[mt][1] = __builtin_amdgcn_logf(lr.y);
            rv[mt][2] = __builtin_amdgcn_logf(lr.z);
            rv[mt][3] = __builtin_amdgcn_logf(lr.w);
        }
        __syncthreads();
        f32x4 sa[2][4];
#pragma unroll
        for (int mt = 0; mt < 2; ++mt)
#pragma unroll
            for (int nt = 0; nt < 4; ++nt) sa[mt][nt] = (f32x4){0.f, 0.f, 0.f, 0.f};
#pragma unroll
        for (int k = 0; k < 8; ++k) {
            bf16x8 av[2];
#pragma unroll
            for (int mt = 0; mt < 2; ++mt)
                av[mt] = ld_bf8(Kt + ((size_t)(b * N_ + i0 + bw + mt * 16 + c16)) * C_ + k * 32 + g * 8);
#pragma unroll
            for (int nt = 0; nt < 4; ++nt) {
                bf16x8 bv = *(const bf16x8*)&sQ[nt * 16 + c16][k * 32 + g * 8];
#pragma unroll
                for (int mt = 0; mt < 2; ++mt)
                    sa[mt][nt] = __builtin_amdgcn_mfma_f32_16x16x32_bf16(av[mt], bv, sa[mt][nt], 0, 0, 0);
            }
        }
#pragma unroll
        for (int mt = 0; mt < 2; ++mt)
#pragma unroll
            for (int nt = 0; nt < 4; ++nt) {
                const int j = nt * 16 + c16;
                unsigned p0 = f2bf(__builtin_amdgcn_exp2f(sa[mt][nt][0] - rv[mt][0]));
                unsigned p1 = f2bf(__builtin_amdgcn_exp2f(sa[mt][nt][1] - rv[mt][1]));
                unsigned p2 = f2bf(__builtin_amdgcn_exp2f(sa[mt][nt][2] - rv[mt][2]));
                unsigned p3 = f2bf(__builtin_amdgcn_exp2f(sa[mt][nt][3] - rv[mt][3]));
                uint2 pk; pk.x = p0 | (p1 << 16); pk.y = p2 | (p3 << 16);
                *(uint2*)&sP[j][bw + mt * 16 + g * 4] = pk;
            }
        __syncthreads();
#pragma unroll
        for (int ks = 0; ks < 8; ++ks) {
            bf16x8 va[2];
#pragma unroll
            for (int mt = 0; mt < 2; ++mt)
                va[mt] = ld_bf8(V + ((size_t)(b * C_ + bw + mt * 16 + c16)) * N_ + i0 + ks * 32 + g * 8);
#pragma unroll
            for (int nt = 0; nt < 4; ++nt) {
                bf16x8 pb = *(const bf16x8*)&sP[nt * 16 + c16][ks * 32 + g * 8];
#pragma unroll
                for (int mt = 0; mt < 2; ++mt)
                    acc[mt][nt] = __builtin_amdgcn_mfma_f32_16x16x32_bf16(va[mt], pb, acc[mt][nt], 0, 0, 0);
            }
        }
    }
#pragma unroll
    for (int mt = 0; mt < 2; ++mt)
#pragma unroll
        for (int nt = 0; nt < 4; ++nt)
#pragma unroll
            for (int r = 0; r < 4; ++r) {
                const int c = bw + mt * 16 + g * 4 + r;
                const int j = jb + nt * 16 + c16;
                atomicAdd(dout + ((size_t)b * C_ + c) * N_ + j, acc[mt][nt][r]);
            }
}

extern "C" void kernel_launch(void* const* d_in, const int* in_sizes, int n_in,
                              void* d_out, int out_size, void* d_ws, size_t ws_size,
                              hipStream_t stream) {
    const float* x_s2  = (const float*)d_in[0];
    const float* x_dem = (const float*)d_in[1];
    const float* Wq = (const float*)d_in[2];
    const float* bq = (const float*)d_in[3];
    const float* Wk = (const float*)d_in[4];
    const float* bk = (const float*)d_in[5];
    const float* Wv = (const float*)d_in[6];
    const float* bv = (const float*)d_in[7];
    float* out = (float*)d_out;

    const size_t MiB = 1024 * 1024;
    char* ws = (char*)d_ws;
    ushort_t* Qt = (ushort_t*)(ws);               // [B][N][C] bf16, 8 MiB
    ushort_t* Kt = (ushort_t*)(ws + 8  * MiB);    // [B][N][C] bf16, pre-scaled
    ushort_t* Vm = (ushort_t*)(ws + 16 * MiB);    // [B][C][N] bf16, 8 MiB
    ushort_t* Vs = (ushort_t*)(ws + 24 * MiB);    // [B][C][N] bf16, V/l, 8 MiB
    float*    lv = (float*)   (ws + 32 * MiB);    // [B][N] row sums, 64 KiB
    ushort_t* PT = (ushort_t*)(ws + 33 * MiB);    // [B][N(j)][N(i)] bf16, 128 MiB
    const bool bigws = ws_size >= 161 * MiB;

    hipMemsetAsync(lv, 0, (size_t)B_ * N_ * sizeof(float), stream);
    // residual: pre-fill output with x_s2; pass B atomically adds O
    hipMemcpyAsync(out, x_s2, (size_t)B_ * C_ * N_ * sizeof(float),
                   hipMemcpyDeviceToDevice, stream);

    proj_t_kernel<<<dim3(N_ / 64, C_ / 64, B_), 256, 0, stream>>>(x_s2, Wq, bq, Qt, C_, 1.0f);
    proj_t_kernel<<<dim3(N_ / 64, C_ / 64, B_), 256, 0, stream>>>(x_dem, Wk, bk, Kt, CD_, SCALE_LOG2E);
    proj_n_kernel<<<dim3(N_ / 64, C_ / 64, B_), 256, 0, stream>>>(x_dem, Wv, bv, Vm, CD_);
    stats_kernel<<<dim3(N_ / 128, N_ / 128, B_), 256, 0, stream>>>(Kt, Qt, lv,
                                                                   bigws ? PT : (ushort_t*)nullptr);
    if (bigws) {
        scale_v_kernel<<<dim3(N_ / 2048, C_, B_), 256, 0, stream>>>(Vm, lv, Vs);
        gemm_out_kernel<<<dim3(N_ / 128, 4, B_), 512, 0, stream>>>(Vs, PT, out);
    } else {
        out_kernel<<<dim3(N_ / 64, 2, B_), 512, 0, stream>>>(Kt, Qt, Vm, lv, out);
    }
}

// Round 6
// 283.678 us; speedup vs baseline: 1.6036x; 1.0132x over previous
//
#include <hip/hip_runtime.h>
#include <hip/hip_bf16.h>
#include <cstdint>

#define B_  4
#define N_  4096
#define C_  256
#define CD_ 64

typedef unsigned short ushort_t;
typedef __bf16 bf16x8 __attribute__((ext_vector_type(8)));
typedef float f32x4 __attribute__((ext_vector_type(4)));

typedef const __attribute__((address_space(1))) void* gas_t;
typedef __attribute__((address_space(3))) void* las_t;

// (1/sqrt(256)) * log2(e): folded into K projection so S' = S_true * log2(e)
static constexpr float SCALE_LOG2E = 0.09016844005556021f;

__device__ __forceinline__ ushort_t f2bf(float x) {
    union { float f; unsigned u; } v; v.f = x;
    unsigned u = v.u;
    unsigned r = (u + 0x7fffu + ((u >> 16) & 1u)) >> 16;  // round-nearest-even
    return (ushort_t)r;
}

__device__ __forceinline__ bf16x8 ld_bf8(const ushort_t* p) {
    return *reinterpret_cast<const bf16x8*>(p);
}

// ---------------------------------------------------------------------------
// Projection producing TRANSPOSED bf16 output dst[b][n][o]  (for Qt, Kt)
// dst = (W @ X + bias) * outScale      (unchanged — proven correct)
// ---------------------------------------------------------------------------
__global__ void proj_t_kernel(const float* __restrict__ X, const float* __restrict__ W,
                              const float* __restrict__ bias, ushort_t* __restrict__ dst,
                              int Cin, float outScale) {
    __shared__ float sX[16][68];
    __shared__ float sW[64][17];
    const int tid = threadIdx.x;
    const int b = blockIdx.z;
    const int oBase = blockIdx.y * 64;
    const int nBase = blockIdx.x * 64;
    const int tx = tid & 15, ty = tid >> 4;
    float acc[4][4] = {};
    for (int k0 = 0; k0 < Cin; k0 += 16) {
        int kk = tid >> 4, nn = (tid & 15) * 4;
        float4 xv = *(const float4*)(X + ((size_t)b * Cin + k0 + kk) * N_ + nBase + nn);
        *(float4*)&sX[kk][nn] = xv;
        int oo = tid >> 2, kc = (tid & 3) * 4;
        float4 wv = *(const float4*)(W + (size_t)(oBase + oo) * Cin + k0 + kc);
        sW[oo][kc + 0] = wv.x; sW[oo][kc + 1] = wv.y;
        sW[oo][kc + 2] = wv.z; sW[oo][kc + 3] = wv.w;
        __syncthreads();
#pragma unroll
        for (int kk2 = 0; kk2 < 16; ++kk2) {
            float4 xr4 = *(float4*)&sX[kk2][tx * 4];
            float xr[4] = {xr4.x, xr4.y, xr4.z, xr4.w};
#pragma unroll
            for (int i = 0; i < 4; ++i) {
                float wv2 = sW[ty * 4 + i][kk2];
#pragma unroll
                for (int j = 0; j < 4; ++j) acc[i][j] += wv2 * xr[j];
            }
        }
        __syncthreads();
    }
    float4 bi4 = *(const float4*)(bias + oBase + ty * 4);
    float bia[4] = {bi4.x, bi4.y, bi4.z, bi4.w};
#pragma unroll
    for (int j = 0; j < 4; ++j) {
        int n = nBase + tx * 4 + j;
        unsigned p0 = f2bf((acc[0][j] + bia[0]) * outScale);
        unsigned p1 = f2bf((acc[1][j] + bia[1]) * outScale);
        unsigned p2 = f2bf((acc[2][j] + bia[2]) * outScale);
        unsigned p3 = f2bf((acc[3][j] + bia[3]) * outScale);
        uint2 pk; pk.x = p0 | (p1 << 16); pk.y = p2 | (p3 << 16);
        *(uint2*)(dst + ((size_t)b * N_ + n) * C_ + oBase + ty * 4) = pk;
    }
}

// ---------------------------------------------------------------------------
// Projection producing NATURAL bf16 output dst[b][o][n]  (for V) — unchanged
// ---------------------------------------------------------------------------
__global__ void proj_n_kernel(const float* __restrict__ X, const float* __restrict__ W,
                              const float* __restrict__ bias, ushort_t* __restrict__ dst,
                              int Cin) {
    __shared__ float sX[16][68];
    __shared__ float sW[64][17];
    const int tid = threadIdx.x;
    const int b = blockIdx.z;
    const int oBase = blockIdx.y * 64;
    const int nBase = blockIdx.x * 64;
    const int tx = tid & 15, ty = tid >> 4;
    float acc[4][4] = {};
    for (int k0 = 0; k0 < Cin; k0 += 16) {
        int kk = tid >> 4, nn = (tid & 15) * 4;
        float4 xv = *(const float4*)(X + ((size_t)b * Cin + k0 + kk) * N_ + nBase + nn);
        *(float4*)&sX[kk][nn] = xv;
        int oo = tid >> 2, kc = (tid & 3) * 4;
        float4 wv = *(const float4*)(W + (size_t)(oBase + oo) * Cin + k0 + kc);
        sW[oo][kc + 0] = wv.x; sW[oo][kc + 1] = wv.y;
        sW[oo][kc + 2] = wv.z; sW[oo][kc + 3] = wv.w;
        __syncthreads();
#pragma unroll
        for (int kk2 = 0; kk2 < 16; ++kk2) {
            float4 xr4 = *(float4*)&sX[kk2][tx * 4];
            float xr[4] = {xr4.x, xr4.y, xr4.z, xr4.w};
#pragma unroll
            for (int i = 0; i < 4; ++i) {
                float wv2 = sW[ty * 4 + i][kk2];
#pragma unroll
                for (int j = 0; j < 4; ++j) acc[i][j] += wv2 * xr[j];
            }
        }
        __syncthreads();
    }
#pragma unroll
    for (int i = 0; i < 4; ++i) {
        int o = oBase + ty * 4 + i;
        float bia = bias[o];
        unsigned p0 = f2bf(acc[i][0] + bia);
        unsigned p1 = f2bf(acc[i][1] + bia);
        unsigned p2 = f2bf(acc[i][2] + bia);
        unsigned p3 = f2bf(acc[i][3] + bia);
        uint2 pk; pk.x = p0 | (p1 << 16); pk.y = p2 | (p3 << 16);
        *(uint2*)(dst + ((size_t)b * C_ + o) * N_ + nBase + tx * 4) = pk;
    }
}

// ---------------------------------------------------------------------------
// Pass A v4: l[b][i] = sum_j exp2(S'[i][j]); if PT != null also store
// P^T[j][i] = exp2(S'[i][j]) bf16.  R5 found WRITE_SIZE = 2.04x PT size:
// 32B-sector stores from the C/D fragment layout amplify 2x at HBM.  Fix:
// epilogue transposes the P tile through LDS (staging smem is free after the
// last K-barrier) and streams FULL 256B rows: per wave-instr 4 rows x 16
// consecutive 16B chunks -> every line written whole.
// ---------------------------------------------------------------------------
__global__ __launch_bounds__(256, 3)
void stats_kernel(const ushort_t* __restrict__ Kt, const ushort_t* __restrict__ Qt,
                  float* __restrict__ l, ushort_t* __restrict__ PT) {
    // union: K-loop staging sA = smem[0..8192), sB = smem[8192..16384);
    // epilogue P-tile sP[128][136] = smem[0..17408)  (+8 pad per row)
    __shared__ ushort_t smem[17408];
    const int tid = threadIdx.x;
    const int lane = tid & 63, g = lane >> 4, c16 = lane & 15;
    const int w = tid >> 6, wi = w >> 1, wj = w & 1;
    const int b = blockIdx.z;
    const int ib = blockIdx.y * 128, jb = blockIdx.x * 128;
    f32x4 acc[4][4];
#pragma unroll
    for (int mt = 0; mt < 4; ++mt)
#pragma unroll
        for (int nt = 0; nt < 4; ++nt) acc[mt][nt] = (f32x4){0.f, 0.f, 0.f, 0.f};

    const int srow = tid >> 3;
    const int sc4 = tid & 7;

    for (int k0 = 0; k0 < 256; k0 += 64) {
#pragma unroll
        for (int q = 0; q < 4; ++q) {
            const int row = q * 32 + srow;
            const int gc = sc4 ^ (row & 7);
            const ushort_t* srcA = Kt + ((size_t)(b * N_ + ib + row)) * C_ + k0 + gc * 8;
            const ushort_t* srcB = Qt + ((size_t)(b * N_ + jb + row)) * C_ + k0 + gc * 8;
            __builtin_amdgcn_global_load_lds((gas_t)srcA, (las_t)&smem[(q * 256 + tid) * 8], 16, 0, 0);
            __builtin_amdgcn_global_load_lds((gas_t)srcB, (las_t)&smem[8192 + (q * 256 + tid) * 8], 16, 0, 0);
        }
        __syncthreads();
#pragma unroll
        for (int ks = 0; ks < 2; ++ks) {
            bf16x8 af[4], bf[4];
#pragma unroll
            for (int mt = 0; mt < 4; ++mt) {
                const int row = wi * 64 + mt * 16 + c16;
                af[mt] = *(const bf16x8*)&smem[row * 64 + (((ks * 4 + g) ^ (row & 7)) * 8)];
            }
#pragma unroll
            for (int nt = 0; nt < 4; ++nt) {
                const int row = wj * 64 + nt * 16 + c16;
                bf[nt] = *(const bf16x8*)&smem[8192 + row * 64 + (((ks * 4 + g) ^ (row & 7)) * 8)];
            }
#pragma unroll
            for (int mt = 0; mt < 4; ++mt)
#pragma unroll
                for (int nt = 0; nt < 4; ++nt)
                    acc[mt][nt] = __builtin_amdgcn_mfma_f32_16x16x32_bf16(af[mt], bf[nt], acc[mt][nt], 0, 0, 0);
        }
        __syncthreads();   // also guarantees staging reads done -> smem reusable
    }
    // epilogue: e = exp2(S'); l row-sum via shuffles (as before); P^T fragment
    // writes go to padded LDS tile.  (i,j) mapping: i = ib+wi*64+mt*16+g*4+r,
    // j = jb+wj*64+nt*16+c16 (absmax-proven R1-R5).
#pragma unroll
    for (int mt = 0; mt < 4; ++mt) {
        float rs[4] = {0.f, 0.f, 0.f, 0.f};
#pragma unroll
        for (int nt = 0; nt < 4; ++nt) {
            float e0 = __builtin_amdgcn_exp2f(acc[mt][nt][0]);
            float e1 = __builtin_amdgcn_exp2f(acc[mt][nt][1]);
            float e2 = __builtin_amdgcn_exp2f(acc[mt][nt][2]);
            float e3 = __builtin_amdgcn_exp2f(acc[mt][nt][3]);
            rs[0] += e0; rs[1] += e1; rs[2] += e2; rs[3] += e3;
            if (PT != nullptr) {
                uint2 pk;
                pk.x = (unsigned)f2bf(e0) | ((unsigned)f2bf(e1) << 16);
                pk.y = (unsigned)f2bf(e2) | ((unsigned)f2bf(e3) << 16);
                const int jl = wj * 64 + nt * 16 + c16;
                const int il = wi * 64 + mt * 16 + g * 4;
                *(uint2*)&smem[jl * 136 + il] = pk;
            }
        }
#pragma unroll
        for (int r = 0; r < 4; ++r) {
            float s = rs[r];
            s += __shfl_xor(s, 1, 64);
            s += __shfl_xor(s, 2, 64);
            s += __shfl_xor(s, 4, 64);
            s += __shfl_xor(s, 8, 64);
            if (c16 == 0)
                atomicAdd(l + (size_t)b * N_ + ib + wi * 64 + mt * 16 + g * 4 + r, s);
        }
    }
    if (PT != nullptr) {
        __syncthreads();
        // stream out: thread t covers chunk (t&15) of rows (t>>4)+16r;
        // per wave-instruction: 4 full 256B rows, perfectly line-aligned.
        const int chb = tid & 15;
        const int rb = tid >> 4;
#pragma unroll
        for (int r = 0; r < 8; ++r) {
            const int jl = r * 16 + rb;
            uint4 v = *(const uint4*)&smem[jl * 136 + chb * 8];
            *(uint4*)(PT + ((size_t)(b * N_ + jb + jl)) * N_ + ib + chb * 8) = v;
        }
    }
}

// ---------------------------------------------------------------------------
// V' = V * rcp(l) elementwise.  grid (N/2048, C, B), block 256, 8 elems/thr.
// ---------------------------------------------------------------------------
__global__ void scale_v_kernel(const ushort_t* __restrict__ Vm, const float* __restrict__ l,
                               ushort_t* __restrict__ Vs) {
    const int i = (blockIdx.x * 256 + threadIdx.x) * 8;
    const int c = blockIdx.y, b = blockIdx.z;
    float4 l0 = *(const float4*)(l + (size_t)b * N_ + i);
    float4 l1 = *(const float4*)(l + (size_t)b * N_ + i + 4);
    float r[8] = {__builtin_amdgcn_rcpf(l0.x), __builtin_amdgcn_rcpf(l0.y),
                  __builtin_amdgcn_rcpf(l0.z), __builtin_amdgcn_rcpf(l0.w),
                  __builtin_amdgcn_rcpf(l1.x), __builtin_amdgcn_rcpf(l1.y),
                  __builtin_amdgcn_rcpf(l1.z), __builtin_amdgcn_rcpf(l1.w)};
    const size_t off = ((size_t)(b * C_ + c)) * N_ + i;
    uint4 v = *(const uint4*)(Vm + off);
    unsigned vw[4] = {v.x, v.y, v.z, v.w};
    uint4 o;
    unsigned* ow = &o.x;
#pragma unroll
    for (int q = 0; q < 4; ++q) {
        union { unsigned u; float f; } lo, hi;
        lo.u = (vw[q] & 0xffffu) << 16;
        hi.u = vw[q] & 0xffff0000u;
        float f0 = lo.f * r[q * 2 + 0];
        float f1 = hi.f * r[q * 2 + 1];
        ow[q] = (unsigned)f2bf(f0) | ((unsigned)f2bf(f1) << 16);
    }
    *(uint4*)(Vs + off) = o;
}

// ---------------------------------------------------------------------------
// Pass B v5: pure GEMM  O[c][j] = sum_i V'[c][i] * PT[j][i], K-split 2
// (atomic fan-in 2 onto residual-prefilled d_out — R2-proven; fan-in 4 is
// not, R3).  m97 structure: 128x128 tile, BK=64, global_load_lds(16B) + XOR
// swizzle.  grid (32 j, 2 ct x 2 kh, B), block 512 (8 waves, 4c x 2j).
// ---------------------------------------------------------------------------
__global__ __launch_bounds__(512, 4)
void gemm_out_kernel(const ushort_t* __restrict__ A /*V'*/, const ushort_t* __restrict__ Bm /*PT*/,
                     float* __restrict__ dout) {
    __shared__ ushort_t sA[128 * 64];
    __shared__ ushort_t sB[128 * 64];
    const int tid = threadIdx.x;
    const int lane = tid & 63, g = lane >> 4, c16 = lane & 15;
    const int w = tid >> 6;
    const int cw = (w & 3) * 32, jw = (w >> 2) * 64;
    const int b = blockIdx.z;
    const int jb = blockIdx.x * 128;
    const int ct = (blockIdx.y & 1) * 128;
    const int kh = (blockIdx.y >> 1) * 2048;

    f32x4 acc[2][4];
#pragma unroll
    for (int mt = 0; mt < 2; ++mt)
#pragma unroll
        for (int nt = 0; nt < 4; ++nt) acc[mt][nt] = (f32x4){0.f, 0.f, 0.f, 0.f};

    const int srow = tid >> 3;   // 0..63; q adds 64
    const int sc8 = tid & 7;

    for (int k0 = 0; k0 < 2048; k0 += 64) {
#pragma unroll
        for (int q = 0; q < 2; ++q) {
            const int row = q * 64 + srow;
            const int gc = sc8 ^ (row & 7);
            const ushort_t* srcA = A + ((size_t)(b * C_ + ct + row)) * N_ + kh + k0 + gc * 8;
            const ushort_t* srcB = Bm + ((size_t)(b * N_ + jb + row)) * N_ + kh + k0 + gc * 8;
            __builtin_amdgcn_global_load_lds((gas_t)srcA, (las_t)&sA[(q * 512 + tid) * 8], 16, 0, 0);
            __builtin_amdgcn_global_load_lds((gas_t)srcB, (las_t)&sB[(q * 512 + tid) * 8], 16, 0, 0);
        }
        __syncthreads();
#pragma unroll
        for (int ks = 0; ks < 2; ++ks) {
            bf16x8 af[2], bfg[4];
#pragma unroll
            for (int mt = 0; mt < 2; ++mt) {
                const int row = cw + mt * 16 + c16;
                af[mt] = *(const bf16x8*)&sA[row * 64 + (((ks * 4 + g) ^ (row & 7)) * 8)];
            }
#pragma unroll
            for (int nt = 0; nt < 4; ++nt) {
                const int row = jw + nt * 16 + c16;
                bfg[nt] = *(const bf16x8*)&sB[row * 64 + (((ks * 4 + g) ^ (row & 7)) * 8)];
            }
#pragma unroll
            for (int mt = 0; mt < 2; ++mt)
#pragma unroll
                for (int nt = 0; nt < 4; ++nt)
                    acc[mt][nt] = __builtin_amdgcn_mfma_f32_16x16x32_bf16(af[mt], bfg[nt], acc[mt][nt], 0, 0, 0);
        }
        __syncthreads();
    }
#pragma unroll
    for (int mt = 0; mt < 2; ++mt)
#pragma unroll
        for (int nt = 0; nt < 4; ++nt)
#pragma unroll
            for (int r = 0; r < 4; ++r) {
                const int c = ct + cw + mt * 16 + g * 4 + r;
                const int j = jb + jw + nt * 16 + c16;
                atomicAdd(dout + ((size_t)b * C_ + c) * N_ + j, acc[mt][nt][r]);
            }
}

// ---------------------------------------------------------------------------
// Fallback Pass B (R4, proven 153 us) — used when ws_size < 161 MiB.
// ---------------------------------------------------------------------------
__global__ __launch_bounds__(512, 4)
void out_kernel(const ushort_t* __restrict__ Kt, const ushort_t* __restrict__ Qt,
                const ushort_t* __restrict__ V, const float* __restrict__ l,
                float* __restrict__ dout) {
    __shared__ ushort_t sQ[64][264];
    __shared__ ushort_t sP[64][264];
    const int tid = threadIdx.x;
    const int w = tid >> 6, lane = tid & 63, g = lane >> 4, c16 = lane & 15;
    const int b = blockIdx.z;
    const int jb = blockIdx.x * 64;
    const int ibase = blockIdx.y * 2048;
    {
        const int jl = tid >> 3, cp = (tid & 7) * 32;
        const ushort_t* src = Qt + ((size_t)(b * N_ + jb + jl)) * C_ + cp;
        uint4 a0 = *(const uint4*)(src);
        uint4 a1 = *(const uint4*)(src + 8);
        uint4 a2 = *(const uint4*)(src + 16);
        uint4 a3 = *(const uint4*)(src + 24);
        *(uint4*)&sQ[jl][cp + 0]  = a0;
        *(uint4*)&sQ[jl][cp + 8]  = a1;
        *(uint4*)&sQ[jl][cp + 16] = a2;
        *(uint4*)&sQ[jl][cp + 24] = a3;
    }
    f32x4 acc[2][4];
#pragma unroll
    for (int mt = 0; mt < 2; ++mt)
#pragma unroll
        for (int nt = 0; nt < 4; ++nt) acc[mt][nt] = (f32x4){0.f, 0.f, 0.f, 0.f};

    const int bw = w * 32;

    for (int ic = 0; ic < 8; ++ic) {
        const int i0 = ibase + ic * 256;
        float rv[2][4];
#pragma unroll
        for (int mt = 0; mt < 2; ++mt) {
            float4 lr = *(const float4*)(l + (size_t)b * N_ + i0 + bw + mt * 16 + g * 4);
            rv[mt][0] = __builtin_amdgcn_logf(lr.x);
            rv[mt][1] = __builtin_amdgcn_logf(lr.y);
            rv[mt][2] = __builtin_amdgcn_logf(lr.z);
            rv[mt][3] = __builtin_amdgcn_logf(lr.w);
        }
        __syncthreads();
        f32x4 sa[2][4];
#pragma unroll
        for (int mt = 0; mt < 2; ++mt)
#pragma unroll
            for (int nt = 0; nt < 4; ++nt) sa[mt][nt] = (f32x4){0.f, 0.f, 0.f, 0.f};
#pragma unroll
        for (int k = 0; k < 8; ++k) {
            bf16x8 av[2];
#pragma unroll
            for (int mt = 0; mt < 2; ++mt)
                av[mt] = ld_bf8(Kt + ((size_t)(b * N_ + i0 + bw + mt * 16 + c16)) * C_ + k * 32 + g * 8);
#pragma unroll
            for (int nt = 0; nt < 4; ++nt) {
                bf16x8 bv = *(const bf16x8*)&sQ[nt * 16 + c16][k * 32 + g * 8];
#pragma unroll
                for (int mt = 0; mt < 2; ++mt)
                    sa[mt][nt] = __builtin_amdgcn_mfma_f32_16x16x32_bf16(av[mt], bv, sa[mt][nt], 0, 0, 0);
            }
        }
#pragma unroll
        for (int mt = 0; mt < 2; ++mt)
#pragma unroll
            for (int nt = 0; nt < 4; ++nt) {
                const int j = nt * 16 + c16;
                unsigned p0 = f2bf(__builtin_amdgcn_exp2f(sa[mt][nt][0] - rv[mt][0]));
                unsigned p1 = f2bf(__builtin_amdgcn_exp2f(sa[mt][nt][1] - rv[mt][1]));
                unsigned p2 = f2bf(__builtin_amdgcn_exp2f(sa[mt][nt][2] - rv[mt][2]));
                unsigned p3 = f2bf(__builtin_amdgcn_exp2f(sa[mt][nt][3] - rv[mt][3]));
                uint2 pk; pk.x = p0 | (p1 << 16); pk.y = p2 | (p3 << 16);
                *(uint2*)&sP[j][bw + mt * 16 + g * 4] = pk;
            }
        __syncthreads();
#pragma unroll
        for (int ks = 0; ks < 8; ++ks) {
            bf16x8 va[2];
#pragma unroll
            for (int mt = 0; mt < 2; ++mt)
                va[mt] = ld_bf8(V + ((size_t)(b * C_ + bw + mt * 16 + c16)) * N_ + i0 + ks * 32 + g * 8);
#pragma unroll
            for (int nt = 0; nt < 4; ++nt) {
                bf16x8 pb = *(const bf16x8*)&sP[nt * 16 + c16][ks * 32 + g * 8];
#pragma unroll
                for (int mt = 0; mt < 2; ++mt)
                    acc[mt][nt] = __builtin_amdgcn_mfma_f32_16x16x32_bf16(va[mt], pb, acc[mt][nt], 0, 0, 0);
            }
        }
    }
#pragma unroll
    for (int mt = 0; mt < 2; ++mt)
#pragma unroll
        for (int nt = 0; nt < 4; ++nt)
#pragma unroll
            for (int r = 0; r < 4; ++r) {
                const int c = bw + mt * 16 + g * 4 + r;
                const int j = jb + nt * 16 + c16;
                atomicAdd(dout + ((size_t)b * C_ + c) * N_ + j, acc[mt][nt][r]);
            }
}

extern "C" void kernel_launch(void* const* d_in, const int* in_sizes, int n_in,
                              void* d_out, int out_size, void* d_ws, size_t ws_size,
                              hipStream_t stream) {
    const float* x_s2  = (const float*)d_in[0];
    const float* x_dem = (const float*)d_in[1];
    const float* Wq = (const float*)d_in[2];
    const float* bq = (const float*)d_in[3];
    const float* Wk = (const float*)d_in[4];
    const float* bk = (const float*)d_in[5];
    const float* Wv = (const float*)d_in[6];
    const float* bv = (const float*)d_in[7];
    float* out = (float*)d_out;

    const size_t MiB = 1024 * 1024;
    char* ws = (char*)d_ws;
    ushort_t* Qt = (ushort_t*)(ws);               // [B][N][C] bf16, 8 MiB
    ushort_t* Kt = (ushort_t*)(ws + 8  * MiB);    // [B][N][C] bf16, pre-scaled
    ushort_t* Vm = (ushort_t*)(ws + 16 * MiB);    // [B][C][N] bf16, 8 MiB
    ushort_t* Vs = (ushort_t*)(ws + 24 * MiB);    // [B][C][N] bf16, V/l, 8 MiB
    float*    lv = (float*)   (ws + 32 * MiB);    // [B][N] row sums, 64 KiB
    ushort_t* PT = (ushort_t*)(ws + 33 * MiB);    // [B][N(j)][N(i)] bf16, 128 MiB
    const bool bigws = ws_size >= 161 * MiB;

    hipMemsetAsync(lv, 0, (size_t)B_ * N_ * sizeof(float), stream);
    // residual: pre-fill output with x_s2; pass B atomically adds O
    hipMemcpyAsync(out, x_s2, (size_t)B_ * C_ * N_ * sizeof(float),
                   hipMemcpyDeviceToDevice, stream);

    proj_t_kernel<<<dim3(N_ / 64, C_ / 64, B_), 256, 0, stream>>>(x_s2, Wq, bq, Qt, C_, 1.0f);
    proj_t_kernel<<<dim3(N_ / 64, C_ / 64, B_), 256, 0, stream>>>(x_dem, Wk, bk, Kt, CD_, SCALE_LOG2E);
    proj_n_kernel<<<dim3(N_ / 64, C_ / 64, B_), 256, 0, stream>>>(x_dem, Wv, bv, Vm, CD_);
    stats_kernel<<<dim3(N_ / 128, N_ / 128, B_), 256, 0, stream>>>(Kt, Qt, lv,
                                                                   bigws ? PT : (ushort_t*)nullptr);
    if (bigws) {
        scale_v_kernel<<<dim3(N_ / 2048, C_, B_), 256, 0, stream>>>(Vm, lv, Vs);
        gemm_out_kernel<<<dim3(N_ / 128, 4, B_), 512, 0, stream>>>(Vs, PT, out);
    } else {
        out_kernel<<<dim3(N_ / 64, 2, B_), 512, 0, stream>>>(Kt, Qt, Vm, lv, out);
    }
}

// Round 8
// 240.001 us; speedup vs baseline: 1.8954x; 1.1820x over previous
//
#include <hip/hip_runtime.h>
#include <hip/hip_bf16.h>
#include <cstdint>

#define B_  4
#define N_  4096
#define C_  256
#define CD_ 64

typedef unsigned short ushort_t;
typedef __bf16 bf16x8 __attribute__((ext_vector_type(8)));
typedef float f32x4 __attribute__((ext_vector_type(4)));

typedef const __attribute__((address_space(1))) void* gas_t;
typedef __attribute__((address_space(3))) void* las_t;

// (1/sqrt(256)) * log2(e): folded into K projection so S' = S_true * log2(e)
static constexpr float SCALE_LOG2E = 0.09016844005556021f;

__device__ __forceinline__ ushort_t f2bf(float x) {
    union { float f; unsigned u; } v; v.f = x;
    unsigned u = v.u;
    unsigned r = (u + 0x7fffu + ((u >> 16) & 1u)) >> 16;  // round-nearest-even
    return (ushort_t)r;
}

__device__ __forceinline__ bf16x8 ld_bf8(const ushort_t* p) {
    return *reinterpret_cast<const bf16x8*>(p);
}

// ---------------------------------------------------------------------------
// MFMA projection -> TRANSPOSED layout dst[b][n][o], o in [ob,ob+64).
// dst = (W @ X + bias) * outScale.  X fp32 [b][Cin][n] cast+transposed into
// LDS (A-frag rows = n); W fp32 cast into LDS (B rows = o).  Tile 128n x 64o,
// BK=64.  R7 BUG FIX: weight staging converted 16 ushorts/thread but stored
// only one uint4 (8) — upper half of every W row was uninitialized LDS -> NaN.
// Now stores both 16B halves.
// ---------------------------------------------------------------------------
__global__ __launch_bounds__(256, 4)
void proj_q_mfma(const float* __restrict__ X, const float* __restrict__ W,
                 const float* __restrict__ bias, ushort_t* __restrict__ dst,
                 int Cin, float outScale) {
    __shared__ ushort_t sX[128][72];   // [n][c] bf16
    __shared__ ushort_t sW[64][72];    // [o][c] bf16
    const int tid = threadIdx.x;
    const int lane = tid & 63, g = lane >> 4, c16 = lane & 15;
    const int w = tid >> 6, wi = w >> 1, wj = w & 1;   // n-half, o-half
    const int b = blockIdx.z, nb = blockIdx.x * 128, ob = blockIdx.y * 64;
    f32x4 acc[4][2];
#pragma unroll
    for (int nt = 0; nt < 4; ++nt)
#pragma unroll
        for (int ot = 0; ot < 2; ++ot) acc[nt][ot] = (f32x4){0.f, 0.f, 0.f, 0.f};

    const int cr = tid >> 5;          // staging: c-row within pass
    const int n0 = (tid & 31) * 4;    // staging: 4 n's

    for (int k0 = 0; k0 < Cin; k0 += 64) {
        // stage X^T: 8 passes of 8c x 128n; coalesced float4 along n
#pragma unroll
        for (int p = 0; p < 8; ++p) {
            const int c = p * 8 + cr;
            float4 xv = *(const float4*)(X + ((size_t)b * Cin + k0 + c) * N_ + nb + n0);
            sX[n0 + 0][c] = f2bf(xv.x);
            sX[n0 + 1][c] = f2bf(xv.y);
            sX[n0 + 2][c] = f2bf(xv.z);
            sX[n0 + 3][c] = f2bf(xv.w);
        }
        // stage W: o = tid>>2, 16 c's per thread (two 16B stores!)
        {
            const int o = tid >> 2, cq = (tid & 3) * 16;
            const float* wsrc = W + (size_t)(ob + o) * Cin + k0 + cq;
            alignas(16) ushort_t tmp[16];
#pragma unroll
            for (int q = 0; q < 16; ++q) tmp[q] = f2bf(wsrc[q]);
            *(uint4*)&sW[o][cq]     = *(uint4*)&tmp[0];
            *(uint4*)&sW[o][cq + 8] = *(uint4*)&tmp[8];
        }
        __syncthreads();
#pragma unroll
        for (int ks = 0; ks < 2; ++ks) {
            bf16x8 af[4], bfr[2];
#pragma unroll
            for (int nt = 0; nt < 4; ++nt)
                af[nt] = *(const bf16x8*)&sX[wi * 64 + nt * 16 + c16][ks * 32 + g * 8];
#pragma unroll
            for (int ot = 0; ot < 2; ++ot)
                bfr[ot] = *(const bf16x8*)&sW[wj * 32 + ot * 16 + c16][ks * 32 + g * 8];
#pragma unroll
            for (int nt = 0; nt < 4; ++nt)
#pragma unroll
                for (int ot = 0; ot < 2; ++ot)
                    acc[nt][ot] = __builtin_amdgcn_mfma_f32_16x16x32_bf16(af[nt], bfr[ot], acc[nt][ot], 0, 0, 0);
        }
        __syncthreads();
    }
    // epilogue: D rows = n (A index: quad*4+reg), cols = o (B index: lane&15)
#pragma unroll
    for (int ot = 0; ot < 2; ++ot) {
        const int o = ob + wj * 32 + ot * 16 + c16;
        const float bia = bias[o];
#pragma unroll
        for (int nt = 0; nt < 4; ++nt) {
#pragma unroll
            for (int r = 0; r < 4; ++r) {
                const int n = nb + wi * 64 + nt * 16 + g * 4 + r;
                dst[((size_t)b * N_ + n) * C_ + o] = f2bf((acc[nt][ot][r] + bia) * outScale);
            }
        }
    }
}

// ---------------------------------------------------------------------------
// Fused K+V MFMA projection from x_dem (Cin=64, single K-iter; shared X tile).
//   Kt[b][n][o] = (Wk@X + bk) * SCALE_LOG2E   (K-part: A=X^T rows n, B=Wk)
//   Vm[b][o][n] = (Wv@X + bv)                 (V-part: A=Wv rows o, B=X^T)
// Tile 128n x 64o.  Same half-store fix as proj_q_mfma.
// ---------------------------------------------------------------------------
__global__ __launch_bounds__(256, 4)
void proj_kv_mfma(const float* __restrict__ X, const float* __restrict__ Wk,
                  const float* __restrict__ bk, const float* __restrict__ Wv,
                  const float* __restrict__ bv, ushort_t* __restrict__ Kt,
                  ushort_t* __restrict__ Vm) {
    __shared__ ushort_t sX[128][72];   // [n][c]
    __shared__ ushort_t sWk[64][72];   // [o][c]
    __shared__ ushort_t sWv[64][72];
    const int tid = threadIdx.x;
    const int lane = tid & 63, g = lane >> 4, c16 = lane & 15;
    const int w = tid >> 6;
    const int b = blockIdx.z, nb = blockIdx.x * 128, ob = blockIdx.y * 64;

    {   // stage X^T (Cin=64): 8 passes of 8c x 128n
        const int cr = tid >> 5, n0 = (tid & 31) * 4;
#pragma unroll
        for (int p = 0; p < 8; ++p) {
            const int c = p * 8 + cr;
            float4 xv = *(const float4*)(X + ((size_t)b * CD_ + c) * N_ + nb + n0);
            sX[n0 + 0][c] = f2bf(xv.x);
            sX[n0 + 1][c] = f2bf(xv.y);
            sX[n0 + 2][c] = f2bf(xv.z);
            sX[n0 + 3][c] = f2bf(xv.w);
        }
        const int o = tid >> 2, cq = (tid & 3) * 16;
        alignas(16) ushort_t tk[16], tv[16];
        const float* ksrc = Wk + (size_t)(ob + o) * CD_ + cq;
        const float* vsrc = Wv + (size_t)(ob + o) * CD_ + cq;
#pragma unroll
        for (int q = 0; q < 16; ++q) { tk[q] = f2bf(ksrc[q]); tv[q] = f2bf(vsrc[q]); }
        *(uint4*)&sWk[o][cq]     = *(uint4*)&tk[0];
        *(uint4*)&sWk[o][cq + 8] = *(uint4*)&tk[8];
        *(uint4*)&sWv[o][cq]     = *(uint4*)&tv[0];
        *(uint4*)&sWv[o][cq + 8] = *(uint4*)&tv[8];
    }
    __syncthreads();
    // ---- K-part: D rows=n, cols=o; wave = (wi n-half, wj o-half) ----
    {
        const int wi = w >> 1, wj = w & 1;
        f32x4 acc[4][2];
#pragma unroll
        for (int nt = 0; nt < 4; ++nt)
#pragma unroll
            for (int ot = 0; ot < 2; ++ot) acc[nt][ot] = (f32x4){0.f, 0.f, 0.f, 0.f};
#pragma unroll
        for (int ks = 0; ks < 2; ++ks) {
            bf16x8 af[4], bfr[2];
#pragma unroll
            for (int nt = 0; nt < 4; ++nt)
                af[nt] = *(const bf16x8*)&sX[wi * 64 + nt * 16 + c16][ks * 32 + g * 8];
#pragma unroll
            for (int ot = 0; ot < 2; ++ot)
                bfr[ot] = *(const bf16x8*)&sWk[wj * 32 + ot * 16 + c16][ks * 32 + g * 8];
#pragma unroll
            for (int nt = 0; nt < 4; ++nt)
#pragma unroll
                for (int ot = 0; ot < 2; ++ot)
                    acc[nt][ot] = __builtin_amdgcn_mfma_f32_16x16x32_bf16(af[nt], bfr[ot], acc[nt][ot], 0, 0, 0);
        }
#pragma unroll
        for (int ot = 0; ot < 2; ++ot) {
            const int o = ob + wj * 32 + ot * 16 + c16;
            const float bia = bk[o];
#pragma unroll
            for (int nt = 0; nt < 4; ++nt)
#pragma unroll
                for (int r = 0; r < 4; ++r) {
                    const int n = nb + wi * 64 + nt * 16 + g * 4 + r;
                    Kt[((size_t)b * N_ + n) * C_ + o] = f2bf((acc[nt][ot][r] + bia) * SCALE_LOG2E);
                }
        }
    }
    // ---- V-part: D rows=o, cols=n; wave = (ow o-half, nw n-half) ----
    {
        const int ow = w & 1, nw = w >> 1;
        f32x4 acc[2][4];
#pragma unroll
        for (int mt = 0; mt < 2; ++mt)
#pragma unroll
            for (int nt = 0; nt < 4; ++nt) acc[mt][nt] = (f32x4){0.f, 0.f, 0.f, 0.f};
#pragma unroll
        for (int ks = 0; ks < 2; ++ks) {
            bf16x8 af[2], bfr[4];
#pragma unroll
            for (int mt = 0; mt < 2; ++mt)
                af[mt] = *(const bf16x8*)&sWv[ow * 32 + mt * 16 + c16][ks * 32 + g * 8];
#pragma unroll
            for (int nt = 0; nt < 4; ++nt)
                bfr[nt] = *(const bf16x8*)&sX[nw * 64 + nt * 16 + c16][ks * 32 + g * 8];
#pragma unroll
            for (int mt = 0; mt < 2; ++mt)
#pragma unroll
                for (int nt = 0; nt < 4; ++nt)
                    acc[mt][nt] = __builtin_amdgcn_mfma_f32_16x16x32_bf16(af[mt], bfr[nt], acc[mt][nt], 0, 0, 0);
        }
#pragma unroll
        for (int mt = 0; mt < 2; ++mt) {
            const float4 bi4 = *(const float4*)(bv + ob + ow * 32 + mt * 16 + g * 4);
            const float bia[4] = {bi4.x, bi4.y, bi4.z, bi4.w};
#pragma unroll
            for (int nt = 0; nt < 4; ++nt) {
                const int n = nb + nw * 64 + nt * 16 + c16;
#pragma unroll
                for (int r = 0; r < 4; ++r) {
                    const int o = ob + ow * 32 + mt * 16 + g * 4 + r;
                    Vm[((size_t)b * C_ + o) * N_ + n] = f2bf(acc[mt][nt][r] + bia[r]);
                }
            }
        }
    }
}

// ---------------------------------------------------------------------------
// Pass A v4 (unchanged from R6): l[b][i] = sum_j exp2(S'[i][j]); PT store via
// epilogue LDS transpose -> full 256B row writes (R6: WRITE 274->147 MB).
// ---------------------------------------------------------------------------
__global__ __launch_bounds__(256, 3)
void stats_kernel(const ushort_t* __restrict__ Kt, const ushort_t* __restrict__ Qt,
                  float* __restrict__ l, ushort_t* __restrict__ PT) {
    __shared__ ushort_t smem[17408];
    const int tid = threadIdx.x;
    const int lane = tid & 63, g = lane >> 4, c16 = lane & 15;
    const int w = tid >> 6, wi = w >> 1, wj = w & 1;
    const int b = blockIdx.z;
    const int ib = blockIdx.y * 128, jb = blockIdx.x * 128;
    f32x4 acc[4][4];
#pragma unroll
    for (int mt = 0; mt < 4; ++mt)
#pragma unroll
        for (int nt = 0; nt < 4; ++nt) acc[mt][nt] = (f32x4){0.f, 0.f, 0.f, 0.f};

    const int srow = tid >> 3;
    const int sc4 = tid & 7;

    for (int k0 = 0; k0 < 256; k0 += 64) {
#pragma unroll
        for (int q = 0; q < 4; ++q) {
            const int row = q * 32 + srow;
            const int gc = sc4 ^ (row & 7);
            const ushort_t* srcA = Kt + ((size_t)(b * N_ + ib + row)) * C_ + k0 + gc * 8;
            const ushort_t* srcB = Qt + ((size_t)(b * N_ + jb + row)) * C_ + k0 + gc * 8;
            __builtin_amdgcn_global_load_lds((gas_t)srcA, (las_t)&smem[(q * 256 + tid) * 8], 16, 0, 0);
            __builtin_amdgcn_global_load_lds((gas_t)srcB, (las_t)&smem[8192 + (q * 256 + tid) * 8], 16, 0, 0);
        }
        __syncthreads();
#pragma unroll
        for (int ks = 0; ks < 2; ++ks) {
            bf16x8 af[4], bf[4];
#pragma unroll
            for (int mt = 0; mt < 4; ++mt) {
                const int row = wi * 64 + mt * 16 + c16;
                af[mt] = *(const bf16x8*)&smem[row * 64 + (((ks * 4 + g) ^ (row & 7)) * 8)];
            }
#pragma unroll
            for (int nt = 0; nt < 4; ++nt) {
                const int row = wj * 64 + nt * 16 + c16;
                bf[nt] = *(const bf16x8*)&smem[8192 + row * 64 + (((ks * 4 + g) ^ (row & 7)) * 8)];
            }
#pragma unroll
            for (int mt = 0; mt < 4; ++mt)
#pragma unroll
                for (int nt = 0; nt < 4; ++nt)
                    acc[mt][nt] = __builtin_amdgcn_mfma_f32_16x16x32_bf16(af[mt], bf[nt], acc[mt][nt], 0, 0, 0);
        }
        __syncthreads();
    }
#pragma unroll
    for (int mt = 0; mt < 4; ++mt) {
        float rs[4] = {0.f, 0.f, 0.f, 0.f};
#pragma unroll
        for (int nt = 0; nt < 4; ++nt) {
            float e0 = __builtin_amdgcn_exp2f(acc[mt][nt][0]);
            float e1 = __builtin_amdgcn_exp2f(acc[mt][nt][1]);
            float e2 = __builtin_amdgcn_exp2f(acc[mt][nt][2]);
            float e3 = __builtin_amdgcn_exp2f(acc[mt][nt][3]);
            rs[0] += e0; rs[1] += e1; rs[2] += e2; rs[3] += e3;
            if (PT != nullptr) {
                uint2 pk;
                pk.x = (unsigned)f2bf(e0) | ((unsigned)f2bf(e1) << 16);
                pk.y = (unsigned)f2bf(e2) | ((unsigned)f2bf(e3) << 16);
                const int jl = wj * 64 + nt * 16 + c16;
                const int il = wi * 64 + mt * 16 + g * 4;
                *(uint2*)&smem[jl * 136 + il] = pk;
            }
        }
#pragma unroll
        for (int r = 0; r < 4; ++r) {
            float s = rs[r];
            s += __shfl_xor(s, 1, 64);
            s += __shfl_xor(s, 2, 64);
            s += __shfl_xor(s, 4, 64);
            s += __shfl_xor(s, 8, 64);
            if (c16 == 0)
                atomicAdd(l + (size_t)b * N_ + ib + wi * 64 + mt * 16 + g * 4 + r, s);
        }
    }
    if (PT != nullptr) {
        __syncthreads();
        const int chb = tid & 15;
        const int rb = tid >> 4;
#pragma unroll
        for (int r = 0; r < 8; ++r) {
            const int jl = r * 16 + rb;
            uint4 v = *(const uint4*)&smem[jl * 136 + chb * 8];
            *(uint4*)(PT + ((size_t)(b * N_ + jb + jl)) * N_ + ib + chb * 8) = v;
        }
    }
}

// ---------------------------------------------------------------------------
// V' = V * rcp(l) elementwise.  (unchanged)
// ---------------------------------------------------------------------------
__global__ void scale_v_kernel(const ushort_t* __restrict__ Vm, const float* __restrict__ l,
                               ushort_t* __restrict__ Vs) {
    const int i = (blockIdx.x * 256 + threadIdx.x) * 8;
    const int c = blockIdx.y, b = blockIdx.z;
    float4 l0 = *(const float4*)(l + (size_t)b * N_ + i);
    float4 l1 = *(const float4*)(l + (size_t)b * N_ + i + 4);
    float r[8] = {__builtin_amdgcn_rcpf(l0.x), __builtin_amdgcn_rcpf(l0.y),
                  __builtin_amdgcn_rcpf(l0.z), __builtin_amdgcn_rcpf(l0.w),
                  __builtin_amdgcn_rcpf(l1.x), __builtin_amdgcn_rcpf(l1.y),
                  __builtin_amdgcn_rcpf(l1.z), __builtin_amdgcn_rcpf(l1.w)};
    const size_t off = ((size_t)(b * C_ + c)) * N_ + i;
    uint4 v = *(const uint4*)(Vm + off);
    unsigned vw[4] = {v.x, v.y, v.z, v.w};
    uint4 o;
    unsigned* ow = &o.x;
#pragma unroll
    for (int q = 0; q < 4; ++q) {
        union { unsigned u; float f; } lo, hi;
        lo.u = (vw[q] & 0xffffu) << 16;
        hi.u = vw[q] & 0xffff0000u;
        float f0 = lo.f * r[q * 2 + 0];
        float f1 = hi.f * r[q * 2 + 1];
        ow[q] = (unsigned)f2bf(f0) | ((unsigned)f2bf(f1) << 16);
    }
    *(uint4*)(Vs + off) = o;
}

// ---------------------------------------------------------------------------
// Pass B v5 (unchanged): pure GEMM O = V'.PT, K-split 2, m97 structure.
// ---------------------------------------------------------------------------
__global__ __launch_bounds__(512, 4)
void gemm_out_kernel(const ushort_t* __restrict__ A /*V'*/, const ushort_t* __restrict__ Bm /*PT*/,
                     float* __restrict__ dout) {
    __shared__ ushort_t sA[128 * 64];
    __shared__ ushort_t sB[128 * 64];
    const int tid = threadIdx.x;
    const int lane = tid & 63, g = lane >> 4, c16 = lane & 15;
    const int w = tid >> 6;
    const int cw = (w & 3) * 32, jw = (w >> 2) * 64;
    const int b = blockIdx.z;
    const int jb = blockIdx.x * 128;
    const int ct = (blockIdx.y & 1) * 128;
    const int kh = (blockIdx.y >> 1) * 2048;

    f32x4 acc[2][4];
#pragma unroll
    for (int mt = 0; mt < 2; ++mt)
#pragma unroll
        for (int nt = 0; nt < 4; ++nt) acc[mt][nt] = (f32x4){0.f, 0.f, 0.f, 0.f};

    const int srow = tid >> 3;
    const int sc8 = tid & 7;

    for (int k0 = 0; k0 < 2048; k0 += 64) {
#pragma unroll
        for (int q = 0; q < 2; ++q) {
            const int row = q * 64 + srow;
            const int gc = sc8 ^ (row & 7);
            const ushort_t* srcA = A + ((size_t)(b * C_ + ct + row)) * N_ + kh + k0 + gc * 8;
            const ushort_t* srcB = Bm + ((size_t)(b * N_ + jb + row)) * N_ + kh + k0 + gc * 8;
            __builtin_amdgcn_global_load_lds((gas_t)srcA, (las_t)&sA[(q * 512 + tid) * 8], 16, 0, 0);
            __builtin_amdgcn_global_load_lds((gas_t)srcB, (las_t)&sB[(q * 512 + tid) * 8], 16, 0, 0);
        }
        __syncthreads();
#pragma unroll
        for (int ks = 0; ks < 2; ++ks) {
            bf16x8 af[2], bfg[4];
#pragma unroll
            for (int mt = 0; mt < 2; ++mt) {
                const int row = cw + mt * 16 + c16;
                af[mt] = *(const bf16x8*)&sA[row * 64 + (((ks * 4 + g) ^ (row & 7)) * 8)];
            }
#pragma unroll
            for (int nt = 0; nt < 4; ++nt) {
                const int row = jw + nt * 16 + c16;
                bfg[nt] = *(const bf16x8*)&sB[row * 64 + (((ks * 4 + g) ^ (row & 7)) * 8)];
            }
#pragma unroll
            for (int mt = 0; mt < 2; ++mt)
#pragma unroll
                for (int nt = 0; nt < 4; ++nt)
                    acc[mt][nt] = __builtin_amdgcn_mfma_f32_16x16x32_bf16(af[mt], bfg[nt], acc[mt][nt], 0, 0, 0);
        }
        __syncthreads();
    }
#pragma unroll
    for (int mt = 0; mt < 2; ++mt)
#pragma unroll
        for (int nt = 0; nt < 4; ++nt)
#pragma unroll
            for (int r = 0; r < 4; ++r) {
                const int c = ct + cw + mt * 16 + g * 4 + r;
                const int j = jb + jw + nt * 16 + c16;
                atomicAdd(dout + ((size_t)b * C_ + c) * N_ + j, acc[mt][nt][r]);
            }
}

// ---------------------------------------------------------------------------
// Fallback Pass B (unchanged; used when ws_size < 161 MiB).
// ---------------------------------------------------------------------------
__global__ __launch_bounds__(512, 4)
void out_kernel(const ushort_t* __restrict__ Kt, const ushort_t* __restrict__ Qt,
                const ushort_t* __restrict__ V, const float* __restrict__ l,
                float* __restrict__ dout) {
    __shared__ ushort_t sQ[64][264];
    __shared__ ushort_t sP[64][264];
    const int tid = threadIdx.x;
    const int w = tid >> 6, lane = tid & 63, g = lane >> 4, c16 = lane & 15;
    const int b = blockIdx.z;
    const int jb = blockIdx.x * 64;
    const int ibase = blockIdx.y * 2048;
    {
        const int jl = tid >> 3, cp = (tid & 7) * 32;
        const ushort_t* src = Qt + ((size_t)(b * N_ + jb + jl)) * C_ + cp;
        uint4 a0 = *(const uint4*)(src);
        uint4 a1 = *(const uint4*)(src + 8);
        uint4 a2 = *(const uint4*)(src + 16);
        uint4 a3 = *(const uint4*)(src + 24);
        *(uint4*)&sQ[jl][cp + 0]  = a0;
        *(uint4*)&sQ[jl][cp + 8]  = a1;
        *(uint4*)&sQ[jl][cp + 16] = a2;
        *(uint4*)&sQ[jl][cp + 24] = a3;
    }
    f32x4 acc[2][4];
#pragma unroll
    for (int mt = 0; mt < 2; ++mt)
#pragma unroll
        for (int nt = 0; nt < 4; ++nt) acc[mt][nt] = (f32x4){0.f, 0.f, 0.f, 0.f};

    const int bw = w * 32;

    for (int ic = 0; ic < 8; ++ic) {
        const int i0 = ibase + ic * 256;
        float rv[2][4];
#pragma unroll
        for (int mt = 0; mt < 2; ++mt) {
            float4 lr = *(const float4*)(l + (size_t)b * N_ + i0 + bw + mt * 16 + g * 4);
            rv[mt][0] = __builtin_amdgcn_logf(lr.x);
            rv[mt][1] = __builtin_amdgcn_logf(lr.y);
            rv[mt][2] = __builtin_amdgcn_logf(lr.z);
            rv[mt][3] = __builtin_amdgcn_logf(lr.w);
        }
        __syncthreads();
        f32x4 sa[2][4];
#pragma unroll
        for (int mt = 0; mt < 2; ++mt)
#pragma unroll
            for (int nt = 0; nt < 4; ++nt) sa[mt][nt] = (f32x4){0.f, 0.f, 0.f, 0.f};
#pragma unroll
        for (int k = 0; k < 8; ++k) {
            bf16x8 av[2];
#pragma unroll
            for (int mt = 0; mt < 2; ++mt)
                av[mt] = ld_bf8(Kt + ((size_t)(b * N_ + i0 + bw + mt * 16 + c16)) * C_ + k * 32 + g * 8);
#pragma unroll
            for (int nt = 0; nt < 4; ++nt) {
                bf16x8 bv = *(const bf16x8*)&sQ[nt * 16 + c16][k * 32 + g * 8];
#pragma unroll
                for (int mt = 0; mt < 2; ++mt)
                    sa[mt][nt] = __builtin_amdgcn_mfma_f32_16x16x32_bf16(av[mt], bv, sa[mt][nt], 0, 0, 0);
            }
        }
#pragma unroll
        for (int mt = 0; mt < 2; ++mt)
#pragma unroll
            for (int nt = 0; nt < 4; ++nt) {
                const int j = nt * 16 + c16;
                unsigned p0 = f2bf(__builtin_amdgcn_exp2f(sa[mt][nt][0] - rv[mt][0]));
                unsigned p1 = f2bf(__builtin_amdgcn_exp2f(sa[mt][nt][1] - rv[mt][1]));
                unsigned p2 = f2bf(__builtin_amdgcn_exp2f(sa[mt][nt][2] - rv[mt][2]));
                unsigned p3 = f2bf(__builtin_amdgcn_exp2f(sa[mt][nt][3] - rv[mt][3]));
                uint2 pk; pk.x = p0 | (p1 << 16); pk.y = p2 | (p3 << 16);
                *(uint2*)&sP[j][bw + mt * 16 + g * 4] = pk;
            }
        __syncthreads();
#pragma unroll
        for (int ks = 0; ks < 8; ++ks) {
            bf16x8 va[2];
#pragma unroll
            for (int mt = 0; mt < 2; ++mt)
                va[mt] = ld_bf8(V + ((size_t)(b * C_ + bw + mt * 16 + c16)) * N_ + i0 + ks * 32 + g * 8);
#pragma unroll
            for (int nt = 0; nt < 4; ++nt) {
                bf16x8 pb = *(const bf16x8*)&sP[nt * 16 + c16][ks * 32 + g * 8];
#pragma unroll
                for (int mt = 0; mt < 2; ++mt)
                    acc[mt][nt] = __builtin_amdgcn_mfma_f32_16x16x32_bf16(va[mt], pb, acc[mt][nt], 0, 0, 0);
            }
        }
    }
#pragma unroll
    for (int mt = 0; mt < 2; ++mt)
#pragma unroll
        for (int nt = 0; nt < 4; ++nt)
#pragma unroll
            for (int r = 0; r < 4; ++r) {
                const int c = bw + mt * 16 + g * 4 + r;
                const int j = jb + nt * 16 + c16;
                atomicAdd(dout + ((size_t)b * C_ + c) * N_ + j, acc[mt][nt][r]);
            }
}

extern "C" void kernel_launch(void* const* d_in, const int* in_sizes, int n_in,
                              void* d_out, int out_size, void* d_ws, size_t ws_size,
                              hipStream_t stream) {
    const float* x_s2  = (const float*)d_in[0];
    const float* x_dem = (const float*)d_in[1];
    const float* Wq = (const float*)d_in[2];
    const float* bq = (const float*)d_in[3];
    const float* Wk = (const float*)d_in[4];
    const float* bk = (const float*)d_in[5];
    const float* Wv = (const float*)d_in[6];
    const float* bv = (const float*)d_in[7];
    float* out = (float*)d_out;

    const size_t MiB = 1024 * 1024;
    char* ws = (char*)d_ws;
    ushort_t* Qt = (ushort_t*)(ws);               // [B][N][C] bf16, 8 MiB
    ushort_t* Kt = (ushort_t*)(ws + 8  * MiB);    // [B][N][C] bf16, pre-scaled
    ushort_t* Vm = (ushort_t*)(ws + 16 * MiB);    // [B][C][N] bf16, 8 MiB
    ushort_t* Vs = (ushort_t*)(ws + 24 * MiB);    // [B][C][N] bf16, V/l, 8 MiB
    float*    lv = (float*)   (ws + 32 * MiB);    // [B][N] row sums, 64 KiB
    ushort_t* PT = (ushort_t*)(ws + 33 * MiB);    // [B][N(j)][N(i)] bf16, 128 MiB
    const bool bigws = ws_size >= 161 * MiB;

    hipMemsetAsync(lv, 0, (size_t)B_ * N_ * sizeof(float), stream);
    // residual: pre-fill output with x_s2; pass B atomically adds O
    hipMemcpyAsync(out, x_s2, (size_t)B_ * C_ * N_ * sizeof(float),
                   hipMemcpyDeviceToDevice, stream);

    proj_q_mfma<<<dim3(N_ / 128, C_ / 64, B_), 256, 0, stream>>>(x_s2, Wq, bq, Qt, C_, 1.0f);
    proj_kv_mfma<<<dim3(N_ / 128, C_ / 64, B_), 256, 0, stream>>>(x_dem, Wk, bk, Wv, bv, Kt, Vm);
    stats_kernel<<<dim3(N_ / 128, N_ / 128, B_), 256, 0, stream>>>(Kt, Qt, lv,
                                                                   bigws ? PT : (ushort_t*)nullptr);
    if (bigws) {
        scale_v_kernel<<<dim3(N_ / 2048, C_, B_), 256, 0, stream>>>(Vm, lv, Vs);
        gemm_out_kernel<<<dim3(N_ / 128, 4, B_), 512, 0, stream>>>(Vs, PT, out);
    } else {
        out_kernel<<<dim3(N_ / 64, 2, B_), 512, 0, stream>>>(Kt, Qt, Vm, lv, out);
    }
}